// Round 6
// baseline (864.687 us; speedup 1.0000x reference)
//
#include <hip/hip_runtime.h>
#include <hip/hip_bf16.h>

#define N_NODES 100000
#define N_EDGES 1600000

typedef float f32x4 __attribute__((ext_vector_type(4)));

// Established facts (bit-identity evidence, rounds 3-5):
//  - edge_index is int32 on device (int64-decode was a no-op)
//  - float inputs are fp32 (bf16 read gave NaN)
//  - OUTPUT IS FLOAT32 (reference dtype), NOT bf16: packed-bf16 writes produced
//    the invariant absmax=3.96875 signature (risk bytes landing mid-embeddings).

// ---------------------------------------------------------------------------
// degree: cnt[dst]++ over all edges (exact grid: 6250*256 = 1.6M)
__global__ void degree_k(const int* __restrict__ ei, int* __restrict__ cnt) {
    int e = blockIdx.x * blockDim.x + threadIdx.x;
    if (e < N_EDGES) atomicAdd(&cnt[ei[N_EDGES + e]], 1);
}

// ---------------------------------------------------------------------------
// GEMM1 (VALU, fp32): c1[n][0..63] = x[n] @ W1_l ; c1[n][64..127] = x[n] @ W1_r
// wave = 64 nodes, lane = node. W addresses are lane-uniform (scalar loads).
__global__ __launch_bounds__(256) void gemm1_k(const float* __restrict__ x,
                                               const float* __restrict__ W1l,
                                               const float* __restrict__ W1r,
                                               float* __restrict__ c1) {
    int wave = blockIdx.x * 4 + (threadIdx.x >> 6);   // 391*4 = 1564 waves
    int lane = threadIdx.x & 63;
    int n = wave * 64 + lane;
    int nc = n < N_NODES ? n : N_NODES - 1;
    const float* xr = x + (size_t)nc * 128;

#pragma unroll
    for (int p = 0; p < 4; ++p) {                     // 4 passes x 32 cols
        const float* Wp = (p < 2) ? (W1l + p * 32) : (W1r + (p - 2) * 32);
        float acc[32];
#pragma unroll
        for (int j = 0; j < 32; ++j) acc[j] = 0.f;
        for (int k = 0; k < 128; ++k) {
            float a = xr[k];
            const float* wr = Wp + k * 64;            // uniform across lanes
#pragma unroll
            for (int j = 0; j < 32; ++j) acc[j] = fmaf(a, wr[j], acc[j]);
        }
        if (n < N_NODES) {
            float* crow = c1 + (size_t)n * 128 + p * 32;
#pragma unroll
            for (int q = 0; q < 8; ++q)
                *(f32x4*)(crow + 4 * q) =
                    (f32x4){acc[4 * q], acc[4 * q + 1], acc[4 * q + 2], acc[4 * q + 3]};
        }
    }
}

// ---------------------------------------------------------------------------
// scatter1: agg1[dst][0..63] += c1[src][0..63]; one wave per edge, lane=feature
__global__ void scatter1_k(const int* __restrict__ ei,
                           const float* __restrict__ c1,
                           float* __restrict__ agg1) {
    int lane = threadIdx.x & 63;
    int w  = (blockIdx.x << 2) + (threadIdx.x >> 6);
    int nw = gridDim.x << 2;
    for (int e = w; e < N_EDGES; e += nw) {
        int s = ei[e], d = ei[N_EDGES + e];
        float v = c1[(size_t)s * 128 + lane];
        atomicAdd(&agg1[(size_t)d * 64 + lane], v);
    }
}

// ---------------------------------------------------------------------------
// node1: h = relu(agg1/max(cnt,1) + c1[:,64:128] + b1), fp32
__global__ void node1_k(const float* __restrict__ agg1,
                        const float* __restrict__ c1,
                        const int* __restrict__ cnt,
                        const float* __restrict__ b1,
                        float* __restrict__ h) {
    int idx = blockIdx.x * blockDim.x + threadIdx.x;  // exact: 25000*256 = 6.4M
    int n = idx >> 6, f = idx & 63;
    int c = cnt[n];
    float cf = (float)(c > 0 ? c : 1);
    float v = agg1[idx] / cf + c1[(size_t)n * 128 + 64 + f] + b1[f];
    h[idx] = v > 0.f ? v : 0.f;
}

// ---------------------------------------------------------------------------
// GEMM2 (VALU, fp32): c2[n][0..31] = h[n] @ W2_l ; c2[n][32..63] = h[n] @ W2_r
__global__ __launch_bounds__(256) void gemm2_k(const float* __restrict__ h,
                                               const float* __restrict__ W2l,
                                               const float* __restrict__ W2r,
                                               float* __restrict__ c2) {
    int wave = blockIdx.x * 4 + (threadIdx.x >> 6);
    int lane = threadIdx.x & 63;
    int n = wave * 64 + lane;
    int nc = n < N_NODES ? n : N_NODES - 1;
    const float* xr = h + (size_t)nc * 64;

#pragma unroll
    for (int p = 0; p < 2; ++p) {                     // 2 passes x 32 cols
        const float* Wp = (p == 0) ? W2l : W2r;
        float acc[32];
#pragma unroll
        for (int j = 0; j < 32; ++j) acc[j] = 0.f;
        for (int k = 0; k < 64; ++k) {
            float a = xr[k];
            const float* wr = Wp + k * 32;            // uniform across lanes
#pragma unroll
            for (int j = 0; j < 32; ++j) acc[j] = fmaf(a, wr[j], acc[j]);
        }
        if (n < N_NODES) {
            float* crow = c2 + (size_t)n * 64 + p * 32;
#pragma unroll
            for (int q = 0; q < 8; ++q)
                *(f32x4*)(crow + 4 * q) =
                    (f32x4){acc[4 * q], acc[4 * q + 1], acc[4 * q + 2], acc[4 * q + 3]};
        }
    }
}

// ---------------------------------------------------------------------------
// scatter2: agg2[dst][0..31] += c2[src][0..31]; half-wave per edge
__global__ void scatter2_k(const int* __restrict__ ei,
                           const float* __restrict__ c2,
                           float* __restrict__ agg2) {
    int lane = threadIdx.x & 63;
    int f = lane & 31, sub = lane >> 5;
    int w  = (blockIdx.x << 2) + (threadIdx.x >> 6);
    int nw = gridDim.x << 2;
    for (int e = w * 2 + sub; e < N_EDGES; e += nw * 2) {
        int s = ei[e], d = ei[N_EDGES + e];
        float v = c2[(size_t)s * 64 + f];
        atomicAdd(&agg2[(size_t)d * 32 + f], v);
    }
}

// ---------------------------------------------------------------------------
// final: emb = relu(agg2/max(cnt,1) + c2[:,32:64] + b2); risk = emb@Wh + bh
// OUTPUT IS FLOAT32: emb at out[0..3.2M), risk at out[3.2M..3.3M)
__global__ void final_k(const float* __restrict__ agg2,
                        const float* __restrict__ c2,
                        const int* __restrict__ cnt,
                        const float* __restrict__ b2,
                        const float* __restrict__ Wh,
                        const float* __restrict__ bh,
                        float* __restrict__ out) {
    int gtid = blockIdx.x * blockDim.x + threadIdx.x;  // 12500*256 -> 50000 waves
    int lane = threadIdx.x & 63;
    int f = lane & 31;
    int n = ((gtid >> 6) << 1) + (lane >> 5);          // 2 nodes per wave
    if (n >= N_NODES) return;
    int c = cnt[n];
    float cf = (float)(c > 0 ? c : 1);
    float v = agg2[(size_t)n * 32 + f] / cf + c2[(size_t)n * 64 + 32 + f] + b2[f];
    v = v > 0.f ? v : 0.f;
    out[(size_t)n * 32 + f] = v;
    float r = v * Wh[f];
#pragma unroll
    for (int m = 16; m; m >>= 1) r += __shfl_xor(r, m, 64);  // stays in half-wave
    if (f == 0) out[(size_t)N_NODES * 32 + n] = r + bh[0];
}

// ---------------------------------------------------------------------------
extern "C" void kernel_launch(void* const* d_in, const int* in_sizes, int n_in,
                              void* d_out, int out_size, void* d_ws, size_t ws_size,
                              hipStream_t stream) {
    const float* x   = (const float*)d_in[0];
    const int*   ei  = (const int*)d_in[1];
    const float* W1l = (const float*)d_in[2];
    const float* b1  = (const float*)d_in[3];
    const float* W1r = (const float*)d_in[4];
    const float* W2l = (const float*)d_in[5];
    const float* b2  = (const float*)d_in[6];
    const float* W2r = (const float*)d_in[7];
    const float* Wh  = (const float*)d_in[8];
    const float* bh  = (const float*)d_in[9];
    float* out = (float*)d_out;

    // workspace layout (bytes):
    //   c1   @ 0.0M       N*128*4 = 51,200,000
    //   h    @ 51.2M      N*64*4  = 25,600,000
    //   c2   @ 76.8M      N*64*4  = 25,600,000
    //   agg1 @ 102.4M     N*64*4  = 25,600,000   (zeroed)
    //   agg2 @ 128.0M     N*32*4  = 12,800,000   (zeroed)
    //   cnt  @ 140.8M     N*4     =    400,000   (zeroed)
    // total 141.2 MB
    char* ws = (char*)d_ws;
    float* c1   = (float*)(ws);
    float* h    = (float*)(ws + 51200000);
    float* c2   = (float*)(ws + 76800000);
    float* agg1 = (float*)(ws + 102400000);
    float* agg2 = (float*)(ws + 128000000);
    int*   cnt  = (int*)(ws + 140800000);

    hipMemsetAsync(ws + 102400000, 0, 38800000, stream);  // agg1+agg2+cnt

    degree_k  <<<6250, 256, 0, stream>>>(ei, cnt);
    gemm1_k   <<<391, 256, 0, stream>>>(x, W1l, W1r, c1);
    scatter1_k<<<4096, 256, 0, stream>>>(ei, c1, agg1);
    node1_k   <<<25000, 256, 0, stream>>>(agg1, c1, cnt, b1, h);
    gemm2_k   <<<391, 256, 0, stream>>>(h, W2l, W2r, c2);
    scatter2_k<<<4096, 256, 0, stream>>>(ei, c2, agg2);
    final_k   <<<12500, 256, 0, stream>>>(agg2, c2, cnt, b2, Wh, bh, out);
}

// Round 7
// 757.373 us; speedup vs baseline: 1.1417x; 1.1417x over previous
//
#include <hip/hip_runtime.h>
#include <hip/hip_bf16.h>

#define N_NODES 100000
#define N_EDGES 1600000

typedef float f32x4 __attribute__((ext_vector_type(4)));

// Established facts:
//  - edge_index int32, float inputs fp32, OUTPUT fp32 (rounds 3-6).
//  - R6 baseline 865us: scatter1_k 334us atomic-bound (WRITE_SIZE=400MB = E*64*4B,
//    VALUBusy 8.5%, HBM 24%). This round: CSR (dst-bucketed) gather-reduce,
//    one write per dst row; node-combine fused into aggregation epilogues.

// ---------------------------------------------------------------------------
// degree: cnt[dst]++ over all edges (exact grid: 6250*256 = 1.6M)
__global__ void degree_k(const int* __restrict__ ei, int* __restrict__ cnt) {
    int e = blockIdx.x * blockDim.x + threadIdx.x;
    if (e < N_EDGES) atomicAdd(&cnt[ei[N_EDGES + e]], 1);
}

// ---------------------------------------------------------------------------
// scan: offsets = exclusive prefix sum of cnt. One block, 1024 threads,
// 98 elems/thread serial + LDS Hillis-Steele over 1024 partials.
__global__ __launch_bounds__(1024) void scan_k(const int* __restrict__ cnt,
                                               int* __restrict__ offsets) {
    __shared__ int part[1024];
    const int CH = 98;                     // 1024*98 = 100352 >= N
    int t = threadIdx.x, base = t * CH;
    int s = 0;
    for (int i = 0; i < CH; ++i) {
        int idx = base + i;
        if (idx < N_NODES) s += cnt[idx];
    }
    part[t] = s;
    __syncthreads();
    for (int off = 1; off < 1024; off <<= 1) {   // inclusive scan
        int v = (t >= off) ? part[t - off] : 0;
        __syncthreads();
        part[t] += v;
        __syncthreads();
    }
    int run = (t == 0) ? 0 : part[t - 1];        // exclusive base for this chunk
    for (int i = 0; i < CH; ++i) {
        int idx = base + i;
        if (idx < N_NODES) { offsets[idx] = run; run += cnt[idx]; }
    }
}

// ---------------------------------------------------------------------------
// fill: csr[offsets[d] + cursor[d]++] = s   (dst-bucketed src list)
__global__ void fill_k(const int* __restrict__ ei, const int* __restrict__ offsets,
                       int* __restrict__ cursor, int* __restrict__ csr) {
    int e = blockIdx.x * blockDim.x + threadIdx.x;
    if (e < N_EDGES) {
        int s = ei[e], d = ei[N_EDGES + e];
        int pos = offsets[d] + atomicAdd(&cursor[d], 1);
        csr[pos] = s;
    }
}

// ---------------------------------------------------------------------------
// GEMM1 (VALU, fp32): c1[n][0..63] = x[n] @ W1_l ; c1[n][64..127] = x[n] @ W1_r
__global__ __launch_bounds__(256) void gemm1_k(const float* __restrict__ x,
                                               const float* __restrict__ W1l,
                                               const float* __restrict__ W1r,
                                               float* __restrict__ c1) {
    int wave = blockIdx.x * 4 + (threadIdx.x >> 6);   // 391*4 = 1564 waves
    int lane = threadIdx.x & 63;
    int n = wave * 64 + lane;
    int nc = n < N_NODES ? n : N_NODES - 1;
    const float* xr = x + (size_t)nc * 128;

#pragma unroll
    for (int p = 0; p < 4; ++p) {
        const float* Wp = (p < 2) ? (W1l + p * 32) : (W1r + (p - 2) * 32);
        float acc[32];
#pragma unroll
        for (int j = 0; j < 32; ++j) acc[j] = 0.f;
        for (int k = 0; k < 128; ++k) {
            float a = xr[k];
            const float* wr = Wp + k * 64;            // lane-uniform
#pragma unroll
            for (int j = 0; j < 32; ++j) acc[j] = fmaf(a, wr[j], acc[j]);
        }
        if (n < N_NODES) {
            float* crow = c1 + (size_t)n * 128 + p * 32;
#pragma unroll
            for (int q = 0; q < 8; ++q)
                *(f32x4*)(crow + 4 * q) =
                    (f32x4){acc[4 * q], acc[4 * q + 1], acc[4 * q + 2], acc[4 * q + 3]};
        }
    }
}

// ---------------------------------------------------------------------------
// agg1 (fused node1): wave per dst node, lane = feature (64).
// h[n] = relu( (sum_{s in in(n)} c1[s][0..63]) / max(deg,1) + c1[n][64..127] + b1 )
__global__ __launch_bounds__(256) void agg1_k(const float* __restrict__ c1,
                                              const int* __restrict__ offsets,
                                              const int* __restrict__ cnt,
                                              const int* __restrict__ csr,
                                              const float* __restrict__ b1,
                                              float* __restrict__ h) {
    int n = blockIdx.x * 4 + (threadIdx.x >> 6);      // 25000*4 = 100000 exact
    int lane = threadIdx.x & 63;
    int beg = offsets[n], deg = cnt[n];
    int e = beg, end = beg + deg;
    float sum = 0.f;
    for (; e + 1 < end; e += 2) {                     // 2 outstanding row loads
        int s0 = csr[e], s1 = csr[e + 1];
        sum += c1[(size_t)s0 * 128 + lane];
        sum += c1[(size_t)s1 * 128 + lane];
    }
    if (e < end) sum += c1[(size_t)csr[e] * 128 + lane];
    float cf = deg > 0 ? (float)deg : 1.f;
    float v = sum / cf + c1[(size_t)n * 128 + 64 + lane] + b1[lane];
    h[(size_t)n * 64 + lane] = v > 0.f ? v : 0.f;
}

// ---------------------------------------------------------------------------
// GEMM2 (VALU, fp32): c2[n][0..31] = h[n] @ W2_l ; c2[n][32..63] = h[n] @ W2_r
__global__ __launch_bounds__(256) void gemm2_k(const float* __restrict__ h,
                                               const float* __restrict__ W2l,
                                               const float* __restrict__ W2r,
                                               float* __restrict__ c2) {
    int wave = blockIdx.x * 4 + (threadIdx.x >> 6);
    int lane = threadIdx.x & 63;
    int n = wave * 64 + lane;
    int nc = n < N_NODES ? n : N_NODES - 1;
    const float* xr = h + (size_t)nc * 64;

#pragma unroll
    for (int p = 0; p < 2; ++p) {
        const float* Wp = (p == 0) ? W2l : W2r;
        float acc[32];
#pragma unroll
        for (int j = 0; j < 32; ++j) acc[j] = 0.f;
        for (int k = 0; k < 64; ++k) {
            float a = xr[k];
            const float* wr = Wp + k * 32;            // lane-uniform
#pragma unroll
            for (int j = 0; j < 32; ++j) acc[j] = fmaf(a, wr[j], acc[j]);
        }
        if (n < N_NODES) {
            float* crow = c2 + (size_t)n * 64 + p * 32;
#pragma unroll
            for (int q = 0; q < 8; ++q)
                *(f32x4*)(crow + 4 * q) =
                    (f32x4){acc[4 * q], acc[4 * q + 1], acc[4 * q + 2], acc[4 * q + 3]};
        }
    }
}

// ---------------------------------------------------------------------------
// agg2 (fused final): half-wave per dst node, f = feature (32).
// emb = relu(gather-mean(c2 left) + c2[n][32..63] + b2); risk = emb@Wh + bh
__global__ __launch_bounds__(256) void agg2_k(const float* __restrict__ c2,
                                              const int* __restrict__ offsets,
                                              const int* __restrict__ cnt,
                                              const int* __restrict__ csr,
                                              const float* __restrict__ b2,
                                              const float* __restrict__ Wh,
                                              const float* __restrict__ bh,
                                              float* __restrict__ out) {
    int gwave = blockIdx.x * 4 + (threadIdx.x >> 6);  // 12500*4 = 50000 waves
    int lane = threadIdx.x & 63;
    int f = lane & 31;
    int n = gwave * 2 + (lane >> 5);                  // 2 nodes/wave, exact 100000
    int beg = offsets[n], deg = cnt[n];
    int e = beg, end = beg + deg;
    float sum = 0.f;
    for (; e + 1 < end; e += 2) {
        int s0 = csr[e], s1 = csr[e + 1];
        sum += c2[(size_t)s0 * 64 + f] + c2[(size_t)s1 * 64 + f];
    }
    if (e < end) sum += c2[(size_t)csr[e] * 64 + f];
    float cf = deg > 0 ? (float)deg : 1.f;
    float v = sum / cf + c2[(size_t)n * 64 + 32 + f] + b2[f];
    v = v > 0.f ? v : 0.f;
    out[(size_t)n * 32 + f] = v;
    float r = v * Wh[f];
#pragma unroll
    for (int m = 16; m; m >>= 1) r += __shfl_xor(r, m, 64);  // stays in half-wave
    if (f == 0) out[(size_t)N_NODES * 32 + n] = r + bh[0];
}

// ---------------------------------------------------------------------------
extern "C" void kernel_launch(void* const* d_in, const int* in_sizes, int n_in,
                              void* d_out, int out_size, void* d_ws, size_t ws_size,
                              hipStream_t stream) {
    const float* x   = (const float*)d_in[0];
    const int*   ei  = (const int*)d_in[1];
    const float* W1l = (const float*)d_in[2];
    const float* b1  = (const float*)d_in[3];
    const float* W1r = (const float*)d_in[4];
    const float* W2l = (const float*)d_in[5];
    const float* b2  = (const float*)d_in[6];
    const float* W2r = (const float*)d_in[7];
    const float* Wh  = (const float*)d_in[8];
    const float* bh  = (const float*)d_in[9];
    float* out = (float*)d_out;

    // workspace layout (bytes):
    //   c1      @ 0.0M     N*128*4 = 51,200,000
    //   h       @ 51.2M    N*64*4  = 25,600,000
    //   c2      @ 76.8M    N*64*4  = 25,600,000
    //   cnt     @ 102.4M   N*4     = 400,000   (zeroed)
    //   cursor  @ 102.8M   N*4     = 400,000   (zeroed)
    //   offsets @ 103.2M   N*4     = 400,000
    //   csr     @ 103.6M   E*4     = 6,400,000
    // total 110.0 MB
    char* ws = (char*)d_ws;
    float* c1      = (float*)(ws);
    float* h       = (float*)(ws + 51200000);
    float* c2      = (float*)(ws + 76800000);
    int*   cnt     = (int*)(ws + 102400000);
    int*   cursor  = (int*)(ws + 102800000);
    int*   offsets = (int*)(ws + 103200000);
    int*   csr     = (int*)(ws + 103600000);

    hipMemsetAsync(ws + 102400000, 0, 800000, stream);  // cnt + cursor

    degree_k<<<6250, 256, 0, stream>>>(ei, cnt);
    scan_k  <<<1, 1024, 0, stream>>>(cnt, offsets);
    fill_k  <<<6250, 256, 0, stream>>>(ei, offsets, cursor, csr);
    gemm1_k <<<391, 256, 0, stream>>>(x, W1l, W1r, c1);
    agg1_k  <<<25000, 256, 0, stream>>>(c1, offsets, cnt, csr, b1, h);
    gemm2_k <<<391, 256, 0, stream>>>(h, W2l, W2r, c2);
    agg2_k  <<<12500, 256, 0, stream>>>(c2, offsets, cnt, csr, b2, Wh, bh, out);
}

// Round 8
// 578.296 us; speedup vs baseline: 1.4952x; 1.3097x over previous
//
#include <hip/hip_runtime.h>
#include <hip/hip_bf16.h>

#define N_NODES 100000
#define N_EDGES 1600000

typedef float f32x4 __attribute__((ext_vector_type(4)));

// Established facts:
//  - edge_index int32, float inputs fp32, OUTPUT fp32 (rounds 3-6).
//  - R6 865us: scatter atomics were the wall (WRITE_SIZE=400MB). R7 CSR: 757us,
//    but single-block scan_k = 198us serial bottleneck (Occupancy 0.17%).
//  - R8: hierarchical scan (98-block partial -> 98-scan -> 98-block apply).

// ---------------------------------------------------------------------------
// degree: cnt[dst]++ over all edges (exact grid: 6250*256 = 1.6M)
__global__ void degree_k(const int* __restrict__ ei, int* __restrict__ cnt) {
    int e = blockIdx.x * blockDim.x + threadIdx.x;
    if (e < N_EDGES) atomicAdd(&cnt[ei[N_EDGES + e]], 1);
}

// ---------------------------------------------------------------------------
// scanA: block b sums cnt[b*1024 .. b*1024+1023] -> bsum[b]   (98 blocks)
__global__ __launch_bounds__(256) void scanA_k(const int* __restrict__ cnt,
                                               int* __restrict__ bsum) {
    __shared__ int red[256];
    int b = blockIdx.x, t = threadIdx.x;
    int base = b * 1024 + t * 4;
    int s = 0;
#pragma unroll
    for (int i = 0; i < 4; ++i) {
        int idx = base + i;
        if (idx < N_NODES) s += cnt[idx];
    }
    red[t] = s;
    __syncthreads();
    for (int off = 128; off; off >>= 1) {
        if (t < off) red[t] += red[t + off];
        __syncthreads();
    }
    if (t == 0) bsum[b] = red[0];
}

// ---------------------------------------------------------------------------
// scanB: exclusive scan of bsum[0..97] -> bbase[0..97]   (1 block, 128 thr)
__global__ __launch_bounds__(128) void scanB_k(const int* __restrict__ bsum,
                                               int* __restrict__ bbase) {
    __shared__ int sh[128];
    int t = threadIdx.x;
    sh[t] = (t < 98) ? bsum[t] : 0;
    __syncthreads();
    for (int off = 1; off < 128; off <<= 1) {
        int v = (t >= off) ? sh[t - off] : 0;
        __syncthreads();
        sh[t] += v;
        __syncthreads();
    }
    if (t < 98) bbase[t] = (t == 0) ? 0 : sh[t - 1];
}

// ---------------------------------------------------------------------------
// scanC: offsets[idx] = bbase[b] + exclusive-intra-block scan   (98 blocks)
__global__ __launch_bounds__(256) void scanC_k(const int* __restrict__ cnt,
                                               const int* __restrict__ bbase,
                                               int* __restrict__ offsets) {
    __shared__ int sh[256];
    int b = blockIdx.x, t = threadIdx.x;
    int base = b * 1024 + t * 4;
    int v[4], s = 0;
#pragma unroll
    for (int i = 0; i < 4; ++i) {
        int idx = base + i;
        v[i] = (idx < N_NODES) ? cnt[idx] : 0;
        s += v[i];
    }
    sh[t] = s;
    __syncthreads();
    for (int off = 1; off < 256; off <<= 1) {
        int x = (t >= off) ? sh[t - off] : 0;
        __syncthreads();
        sh[t] += x;
        __syncthreads();
    }
    int run = bbase[b] + ((t == 0) ? 0 : sh[t - 1]);
#pragma unroll
    for (int i = 0; i < 4; ++i) {
        int idx = base + i;
        if (idx < N_NODES) { offsets[idx] = run; run += v[i]; }
    }
}

// ---------------------------------------------------------------------------
// fill: csr[offsets[d] + cursor[d]++] = s   (dst-bucketed src list)
__global__ void fill_k(const int* __restrict__ ei, const int* __restrict__ offsets,
                       int* __restrict__ cursor, int* __restrict__ csr) {
    int e = blockIdx.x * blockDim.x + threadIdx.x;
    if (e < N_EDGES) {
        int s = ei[e], d = ei[N_EDGES + e];
        int pos = offsets[d] + atomicAdd(&cursor[d], 1);
        csr[pos] = s;
    }
}

// ---------------------------------------------------------------------------
// GEMM1 (VALU, fp32): c1[n][0..63] = x[n] @ W1_l ; c1[n][64..127] = x[n] @ W1_r
__global__ __launch_bounds__(256) void gemm1_k(const float* __restrict__ x,
                                               const float* __restrict__ W1l,
                                               const float* __restrict__ W1r,
                                               float* __restrict__ c1) {
    int wave = blockIdx.x * 4 + (threadIdx.x >> 6);   // 391*4 = 1564 waves
    int lane = threadIdx.x & 63;
    int n = wave * 64 + lane;
    int nc = n < N_NODES ? n : N_NODES - 1;
    const float* xr = x + (size_t)nc * 128;

#pragma unroll
    for (int p = 0; p < 4; ++p) {
        const float* Wp = (p < 2) ? (W1l + p * 32) : (W1r + (p - 2) * 32);
        float acc[32];
#pragma unroll
        for (int j = 0; j < 32; ++j) acc[j] = 0.f;
        for (int k = 0; k < 128; ++k) {
            float a = xr[k];
            const float* wr = Wp + k * 64;            // lane-uniform
#pragma unroll
            for (int j = 0; j < 32; ++j) acc[j] = fmaf(a, wr[j], acc[j]);
        }
        if (n < N_NODES) {
            float* crow = c1 + (size_t)n * 128 + p * 32;
#pragma unroll
            for (int q = 0; q < 8; ++q)
                *(f32x4*)(crow + 4 * q) =
                    (f32x4){acc[4 * q], acc[4 * q + 1], acc[4 * q + 2], acc[4 * q + 3]};
        }
    }
}

// ---------------------------------------------------------------------------
// agg1 (fused node1): wave per dst node, lane = feature (64).
__global__ __launch_bounds__(256) void agg1_k(const float* __restrict__ c1,
                                              const int* __restrict__ offsets,
                                              const int* __restrict__ cnt,
                                              const int* __restrict__ csr,
                                              const float* __restrict__ b1,
                                              float* __restrict__ h) {
    int n = blockIdx.x * 4 + (threadIdx.x >> 6);      // 25000*4 = 100000 exact
    int lane = threadIdx.x & 63;
    int beg = offsets[n], deg = cnt[n];
    int e = beg, end = beg + deg;
    float sum = 0.f;
    for (; e + 1 < end; e += 2) {
        int s0 = csr[e], s1 = csr[e + 1];
        sum += c1[(size_t)s0 * 128 + lane];
        sum += c1[(size_t)s1 * 128 + lane];
    }
    if (e < end) sum += c1[(size_t)csr[e] * 128 + lane];
    float cf = deg > 0 ? (float)deg : 1.f;
    float v = sum / cf + c1[(size_t)n * 128 + 64 + lane] + b1[lane];
    h[(size_t)n * 64 + lane] = v > 0.f ? v : 0.f;
}

// ---------------------------------------------------------------------------
// GEMM2 (VALU, fp32): c2[n][0..31] = h[n] @ W2_l ; c2[n][32..63] = h[n] @ W2_r
__global__ __launch_bounds__(256) void gemm2_k(const float* __restrict__ h,
                                               const float* __restrict__ W2l,
                                               const float* __restrict__ W2r,
                                               float* __restrict__ c2) {
    int wave = blockIdx.x * 4 + (threadIdx.x >> 6);
    int lane = threadIdx.x & 63;
    int n = wave * 64 + lane;
    int nc = n < N_NODES ? n : N_NODES - 1;
    const float* xr = h + (size_t)nc * 64;

#pragma unroll
    for (int p = 0; p < 2; ++p) {
        const float* Wp = (p == 0) ? W2l : W2r;
        float acc[32];
#pragma unroll
        for (int j = 0; j < 32; ++j) acc[j] = 0.f;
        for (int k = 0; k < 64; ++k) {
            float a = xr[k];
            const float* wr = Wp + k * 32;            // lane-uniform
#pragma unroll
            for (int j = 0; j < 32; ++j) acc[j] = fmaf(a, wr[j], acc[j]);
        }
        if (n < N_NODES) {
            float* crow = c2 + (size_t)n * 64 + p * 32;
#pragma unroll
            for (int q = 0; q < 8; ++q)
                *(f32x4*)(crow + 4 * q) =
                    (f32x4){acc[4 * q], acc[4 * q + 1], acc[4 * q + 2], acc[4 * q + 3]};
        }
    }
}

// ---------------------------------------------------------------------------
// agg2 (fused final): half-wave per dst node, f = feature (32).
__global__ __launch_bounds__(256) void agg2_k(const float* __restrict__ c2,
                                              const int* __restrict__ offsets,
                                              const int* __restrict__ cnt,
                                              const int* __restrict__ csr,
                                              const float* __restrict__ b2,
                                              const float* __restrict__ Wh,
                                              const float* __restrict__ bh,
                                              float* __restrict__ out) {
    int gwave = blockIdx.x * 4 + (threadIdx.x >> 6);  // 12500*4 = 50000 waves
    int lane = threadIdx.x & 63;
    int f = lane & 31;
    int n = gwave * 2 + (lane >> 5);                  // 2 nodes/wave, exact 100000
    int beg = offsets[n], deg = cnt[n];
    int e = beg, end = beg + deg;
    float sum = 0.f;
    for (; e + 1 < end; e += 2) {
        int s0 = csr[e], s1 = csr[e + 1];
        sum += c2[(size_t)s0 * 64 + f] + c2[(size_t)s1 * 64 + f];
    }
    if (e < end) sum += c2[(size_t)csr[e] * 64 + f];
    float cf = deg > 0 ? (float)deg : 1.f;
    float v = sum / cf + c2[(size_t)n * 64 + 32 + f] + b2[f];
    v = v > 0.f ? v : 0.f;
    out[(size_t)n * 32 + f] = v;
    float r = v * Wh[f];
#pragma unroll
    for (int m = 16; m; m >>= 1) r += __shfl_xor(r, m, 64);  // stays in half-wave
    if (f == 0) out[(size_t)N_NODES * 32 + n] = r + bh[0];
}

// ---------------------------------------------------------------------------
extern "C" void kernel_launch(void* const* d_in, const int* in_sizes, int n_in,
                              void* d_out, int out_size, void* d_ws, size_t ws_size,
                              hipStream_t stream) {
    const float* x   = (const float*)d_in[0];
    const int*   ei  = (const int*)d_in[1];
    const float* W1l = (const float*)d_in[2];
    const float* b1  = (const float*)d_in[3];
    const float* W1r = (const float*)d_in[4];
    const float* W2l = (const float*)d_in[5];
    const float* b2  = (const float*)d_in[6];
    const float* W2r = (const float*)d_in[7];
    const float* Wh  = (const float*)d_in[8];
    const float* bh  = (const float*)d_in[9];
    float* out = (float*)d_out;

    // workspace layout (bytes):
    //   c1      @ 0.0M     N*128*4 = 51,200,000
    //   h       @ 51.2M    N*64*4  = 25,600,000
    //   c2      @ 76.8M    N*64*4  = 25,600,000
    //   cnt     @ 102.4M   N*4     = 400,000   (zeroed)
    //   cursor  @ 102.8M   N*4     = 400,000   (zeroed)
    //   offsets @ 103.2M   N*4     = 400,000
    //   csr     @ 103.6M   E*4     = 6,400,000
    //   bsum    @ 110.0M   98*4    (pad 1024)
    //   bbase   @ 110.0M+1k 98*4   (pad 1024)
    char* ws = (char*)d_ws;
    float* c1      = (float*)(ws);
    float* h       = (float*)(ws + 51200000);
    float* c2      = (float*)(ws + 76800000);
    int*   cnt     = (int*)(ws + 102400000);
    int*   cursor  = (int*)(ws + 102800000);
    int*   offsets = (int*)(ws + 103200000);
    int*   csr     = (int*)(ws + 103600000);
    int*   bsum    = (int*)(ws + 110000000);
    int*   bbase   = (int*)(ws + 110001024);

    hipMemsetAsync(ws + 102400000, 0, 800000, stream);  // cnt + cursor

    degree_k<<<6250, 256, 0, stream>>>(ei, cnt);
    scanA_k <<<98, 256, 0, stream>>>(cnt, bsum);
    scanB_k <<<1, 128, 0, stream>>>(bsum, bbase);
    scanC_k <<<98, 256, 0, stream>>>(cnt, bbase, offsets);
    fill_k  <<<6250, 256, 0, stream>>>(ei, offsets, cursor, csr);
    gemm1_k <<<391, 256, 0, stream>>>(x, W1l, W1r, c1);
    agg1_k  <<<25000, 256, 0, stream>>>(c1, offsets, cnt, csr, b1, h);
    gemm2_k <<<391, 256, 0, stream>>>(h, W2l, W2r, c2);
    agg2_k  <<<12500, 256, 0, stream>>>(c2, offsets, cnt, csr, b2, Wh, bh, out);
}

// Round 9
// 447.071 us; speedup vs baseline: 1.9341x; 1.2935x over previous
//
#include <hip/hip_runtime.h>
#include <hip/hip_bf16.h>

#define N_NODES 100000
#define N_EDGES 1600000

typedef __bf16 bf16x8 __attribute__((ext_vector_type(8)));
typedef float  f32x4  __attribute__((ext_vector_type(4)));

// Established facts:
//  - edge_index int32, float inputs fp32, OUTPUT fp32 (rounds 3-6).
//  - R6 865us (scatter atomics, WRITE=400MB) -> R7 757 (CSR) -> R8 578
//    (hierarchical scan). R8 top: gemm1_k 130us latency-bound (VALUBusy 16%,
//    Occ 16%, grid 391). R9: MFMA GEMMs (m89/m92 layouts) + bf16 gather halves
//    (c1l/c2l bf16, roots fp32) to halve agg gather traffic.

// ---------------------------------------------------------------------------
// degree: cnt[dst]++ over all edges (exact grid: 6250*256 = 1.6M)
__global__ void degree_k(const int* __restrict__ ei, int* __restrict__ cnt) {
    int e = blockIdx.x * blockDim.x + threadIdx.x;
    if (e < N_EDGES) atomicAdd(&cnt[ei[N_EDGES + e]], 1);
}

// ---------------------------------------------------------------------------
// scanA: block b sums cnt[b*1024 .. +1023] -> bsum[b]   (98 blocks)
__global__ __launch_bounds__(256) void scanA_k(const int* __restrict__ cnt,
                                               int* __restrict__ bsum) {
    __shared__ int red[256];
    int b = blockIdx.x, t = threadIdx.x;
    int base = b * 1024 + t * 4;
    int s = 0;
#pragma unroll
    for (int i = 0; i < 4; ++i) {
        int idx = base + i;
        if (idx < N_NODES) s += cnt[idx];
    }
    red[t] = s;
    __syncthreads();
    for (int off = 128; off; off >>= 1) {
        if (t < off) red[t] += red[t + off];
        __syncthreads();
    }
    if (t == 0) bsum[b] = red[0];
}

// ---------------------------------------------------------------------------
// scanB: exclusive scan of bsum[0..97] -> bbase[0..97]   (1 block, 128 thr)
__global__ __launch_bounds__(128) void scanB_k(const int* __restrict__ bsum,
                                               int* __restrict__ bbase) {
    __shared__ int sh[128];
    int t = threadIdx.x;
    sh[t] = (t < 98) ? bsum[t] : 0;
    __syncthreads();
    for (int off = 1; off < 128; off <<= 1) {
        int v = (t >= off) ? sh[t - off] : 0;
        __syncthreads();
        sh[t] += v;
        __syncthreads();
    }
    if (t < 98) bbase[t] = (t == 0) ? 0 : sh[t - 1];
}

// ---------------------------------------------------------------------------
// scanC: offsets[idx] = bbase[b] + exclusive intra-block scan   (98 blocks)
__global__ __launch_bounds__(256) void scanC_k(const int* __restrict__ cnt,
                                               const int* __restrict__ bbase,
                                               int* __restrict__ offsets) {
    __shared__ int sh[256];
    int b = blockIdx.x, t = threadIdx.x;
    int base = b * 1024 + t * 4;
    int v[4], s = 0;
#pragma unroll
    for (int i = 0; i < 4; ++i) {
        int idx = base + i;
        v[i] = (idx < N_NODES) ? cnt[idx] : 0;
        s += v[i];
    }
    sh[t] = s;
    __syncthreads();
    for (int off = 1; off < 256; off <<= 1) {
        int x = (t >= off) ? sh[t - off] : 0;
        __syncthreads();
        sh[t] += x;
        __syncthreads();
    }
    int run = bbase[b] + ((t == 0) ? 0 : sh[t - 1]);
#pragma unroll
    for (int i = 0; i < 4; ++i) {
        int idx = base + i;
        if (idx < N_NODES) { offsets[idx] = run; run += v[i]; }
    }
}

// ---------------------------------------------------------------------------
// fill: csr[offsets[d] + cursor[d]++] = s   (dst-bucketed src list)
__global__ void fill_k(const int* __restrict__ ei, const int* __restrict__ offsets,
                       int* __restrict__ cursor, int* __restrict__ csr) {
    int e = blockIdx.x * blockDim.x + threadIdx.x;
    if (e < N_EDGES) {
        int s = ei[e], d = ei[N_EDGES + e];
        int pos = offsets[d] + atomicAdd(&cursor[d], 1);
        csr[pos] = s;
    }
}

// ---------------------------------------------------------------------------
// GEMM1 (MFMA 16x16x32 bf16): [c1l | c1r] = x @ [W1_l | W1_r]
// c1l bf16 [N,64] (gathered by agg1), c1r fp32 [N,64] (root term, exact).
__global__ __launch_bounds__(256) void gemm1_k(const float* __restrict__ x,
                                               const float* __restrict__ W1l,
                                               const float* __restrict__ W1r,
                                               __bf16* __restrict__ c1l,
                                               float* __restrict__ c1r) {
    __shared__ __bf16 Bt[128 * 136];   // B^T[n][k], stride 136 = 128+8 pad
    int tid = threadIdx.x;
    for (int idx = tid; idx < 8192; idx += 256) {   // W is [128][64] each
        int k = idx >> 6, n = idx & 63;
        Bt[n * 136 + k]        = (__bf16)W1l[idx];
        Bt[(n + 64) * 136 + k] = (__bf16)W1r[idx];
    }
    __syncthreads();

    int lane = tid & 63, wave = tid >> 6;
    int mbase = blockIdx.x * 64 + wave * 16;        // 1563 blocks * 64 rows
    int col  = lane & 15;
    int kgrp = (lane >> 4) << 3;                    // 0,8,16,24
    int mrow = mbase + col;
    int mclamp = mrow < N_NODES ? mrow : N_NODES - 1;
    const float* arow = x + (size_t)mclamp * 128;

    f32x4 acc[8];
#pragma unroll
    for (int i = 0; i < 8; ++i) acc[i] = (f32x4){0.f, 0.f, 0.f, 0.f};

#pragma unroll
    for (int ks = 0; ks < 4; ++ks) {
        int kk = ks * 32 + kgrp;
        f32x4 a0 = *(const f32x4*)(arow + kk);
        f32x4 a1 = *(const f32x4*)(arow + kk + 4);
        bf16x8 a;
#pragma unroll
        for (int i = 0; i < 4; ++i) { a[i] = (__bf16)a0[i]; a[i + 4] = (__bf16)a1[i]; }
#pragma unroll
        for (int nt = 0; nt < 8; ++nt) {
            bf16x8 b = *(const bf16x8*)(Bt + (nt * 16 + col) * 136 + kk);
            acc[nt] = __builtin_amdgcn_mfma_f32_16x16x32_bf16(a, b, acc[nt], 0, 0, 0);
        }
    }

    // C/D: col = lane&15, row = (lane>>4)*4 + reg   [m89-verified]
    int r0 = mbase + ((lane >> 4) << 2);
#pragma unroll
    for (int r = 0; r < 4; ++r) {
        int m = r0 + r;
        if (m < N_NODES) {
#pragma unroll
            for (int nt = 0; nt < 4; ++nt)
                c1l[(size_t)m * 64 + nt * 16 + col] = (__bf16)acc[nt][r];
#pragma unroll
            for (int nt = 4; nt < 8; ++nt)
                c1r[(size_t)m * 64 + (nt - 4) * 16 + col] = acc[nt][r];
        }
    }
}

// ---------------------------------------------------------------------------
// agg1 (fused node1): wave per dst node, lane = feature (64).
// h[n] = relu( mean_gather(c1l) + c1r[n] + b1 )  -> bf16
__global__ __launch_bounds__(256) void agg1_k(const __bf16* __restrict__ c1l,
                                              const float* __restrict__ c1r,
                                              const int* __restrict__ offsets,
                                              const int* __restrict__ cnt,
                                              const int* __restrict__ csr,
                                              const float* __restrict__ b1,
                                              __bf16* __restrict__ h) {
    int n = blockIdx.x * 4 + (threadIdx.x >> 6);    // 25000*4 = 100000 exact
    int lane = threadIdx.x & 63;
    int beg = offsets[n], deg = cnt[n];
    int e = beg, end = beg + deg;
    float sum = 0.f;
    for (; e + 1 < end; e += 2) {                   // 2 outstanding gathers
        int s0 = csr[e], s1 = csr[e + 1];
        sum += (float)c1l[(size_t)s0 * 64 + lane];
        sum += (float)c1l[(size_t)s1 * 64 + lane];
    }
    if (e < end) sum += (float)c1l[(size_t)csr[e] * 64 + lane];
    float cf = deg > 0 ? (float)deg : 1.f;
    float v = sum / cf + c1r[(size_t)n * 64 + lane] + b1[lane];
    h[(size_t)n * 64 + lane] = (__bf16)(v > 0.f ? v : 0.f);
}

// ---------------------------------------------------------------------------
// GEMM2 (MFMA): [c2l | c2r] = h @ [W2_l | W2_r], h bf16 [N,64].
__global__ __launch_bounds__(256) void gemm2_k(const __bf16* __restrict__ h,
                                               const float* __restrict__ W2l,
                                               const float* __restrict__ W2r,
                                               __bf16* __restrict__ c2l,
                                               float* __restrict__ c2r) {
    __shared__ __bf16 Bt[64 * 72];   // stride 72 = 64+8 pad
    int tid = threadIdx.x;
    for (int idx = tid; idx < 2048; idx += 256) {   // W2 is [64][32] each
        int k = idx >> 5, n = idx & 31;
        Bt[n * 72 + k]        = (__bf16)W2l[idx];
        Bt[(n + 32) * 72 + k] = (__bf16)W2r[idx];
    }
    __syncthreads();

    int lane = tid & 63, wave = tid >> 6;
    int mbase = blockIdx.x * 64 + wave * 16;
    int col  = lane & 15;
    int kgrp = (lane >> 4) << 3;
    int mrow = mbase + col;
    int mclamp = mrow < N_NODES ? mrow : N_NODES - 1;
    const __bf16* arow = h + (size_t)mclamp * 64;

    f32x4 acc[4];
#pragma unroll
    for (int i = 0; i < 4; ++i) acc[i] = (f32x4){0.f, 0.f, 0.f, 0.f};

#pragma unroll
    for (int ks = 0; ks < 2; ++ks) {
        int kk = ks * 32 + kgrp;
        bf16x8 a = *(const bf16x8*)(arow + kk);
#pragma unroll
        for (int nt = 0; nt < 4; ++nt) {
            bf16x8 b = *(const bf16x8*)(Bt + (nt * 16 + col) * 72 + kk);
            acc[nt] = __builtin_amdgcn_mfma_f32_16x16x32_bf16(a, b, acc[nt], 0, 0, 0);
        }
    }

    int r0 = mbase + ((lane >> 4) << 2);
#pragma unroll
    for (int r = 0; r < 4; ++r) {
        int m = r0 + r;
        if (m < N_NODES) {
#pragma unroll
            for (int nt = 0; nt < 2; ++nt)
                c2l[(size_t)m * 32 + nt * 16 + col] = (__bf16)acc[nt][r];
#pragma unroll
            for (int nt = 2; nt < 4; ++nt)
                c2r[(size_t)m * 32 + (nt - 2) * 16 + col] = acc[nt][r];
        }
    }
}

// ---------------------------------------------------------------------------
// agg2 (fused final): half-wave per dst node, f = feature (32).
__global__ __launch_bounds__(256) void agg2_k(const __bf16* __restrict__ c2l,
                                              const float* __restrict__ c2r,
                                              const int* __restrict__ offsets,
                                              const int* __restrict__ cnt,
                                              const int* __restrict__ csr,
                                              const float* __restrict__ b2,
                                              const float* __restrict__ Wh,
                                              const float* __restrict__ bh,
                                              float* __restrict__ out) {
    int gwave = blockIdx.x * 4 + (threadIdx.x >> 6); // 12500*4 = 50000 waves
    int lane = threadIdx.x & 63;
    int f = lane & 31;
    int n = gwave * 2 + (lane >> 5);                 // 2 nodes/wave, exact
    int beg = offsets[n], deg = cnt[n];
    int e = beg, end = beg + deg;
    float sum = 0.f;
    for (; e + 1 < end; e += 2) {
        int s0 = csr[e], s1 = csr[e + 1];
        sum += (float)c2l[(size_t)s0 * 32 + f] + (float)c2l[(size_t)s1 * 32 + f];
    }
    if (e < end) sum += (float)c2l[(size_t)csr[e] * 32 + f];
    float cf = deg > 0 ? (float)deg : 1.f;
    float v = sum / cf + c2r[(size_t)n * 32 + f] + b2[f];
    v = v > 0.f ? v : 0.f;
    out[(size_t)n * 32 + f] = v;
    float r = v * Wh[f];
#pragma unroll
    for (int m = 16; m; m >>= 1) r += __shfl_xor(r, m, 64);  // stays in half-wave
    if (f == 0) out[(size_t)N_NODES * 32 + n] = r + bh[0];
}

// ---------------------------------------------------------------------------
extern "C" void kernel_launch(void* const* d_in, const int* in_sizes, int n_in,
                              void* d_out, int out_size, void* d_ws, size_t ws_size,
                              hipStream_t stream) {
    const float* x   = (const float*)d_in[0];
    const int*   ei  = (const int*)d_in[1];
    const float* W1l = (const float*)d_in[2];
    const float* b1  = (const float*)d_in[3];
    const float* W1r = (const float*)d_in[4];
    const float* W2l = (const float*)d_in[5];
    const float* b2  = (const float*)d_in[6];
    const float* W2r = (const float*)d_in[7];
    const float* Wh  = (const float*)d_in[8];
    const float* bh  = (const float*)d_in[9];
    float* out = (float*)d_out;

    // workspace layout (bytes):
    //   c1l     @ 0.0M     N*64*2 = 12,800,000  (bf16, gathered)
    //   c1r     @ 12.8M    N*64*4 = 25,600,000  (fp32 root)
    //   h       @ 38.4M    N*64*2 = 12,800,000  (bf16)
    //   c2l     @ 51.2M    N*32*2 =  6,400,000  (bf16, gathered)
    //   c2r     @ 57.6M    N*32*4 = 12,800,000  (fp32 root)
    //   cnt     @ 70.4M    N*4    = 400,000   (zeroed)
    //   cursor  @ 70.8M    N*4    = 400,000   (zeroed)
    //   offsets @ 71.2M    N*4    = 400,000
    //   csr     @ 71.6M    E*4    = 6,400,000
    //   bsum    @ 78.0M    98*4   (pad 1024)
    //   bbase   @ 78.0M+1k 98*4
    char* ws = (char*)d_ws;
    __bf16* c1l     = (__bf16*)(ws);
    float*  c1r     = (float*)(ws + 12800000);
    __bf16* h       = (__bf16*)(ws + 38400000);
    __bf16* c2l     = (__bf16*)(ws + 51200000);
    float*  c2r     = (float*)(ws + 57600000);
    int*    cnt     = (int*)(ws + 70400000);
    int*    cursor  = (int*)(ws + 70800000);
    int*    offsets = (int*)(ws + 71200000);
    int*    csr     = (int*)(ws + 71600000);
    int*    bsum    = (int*)(ws + 78000000);
    int*    bbase   = (int*)(ws + 78001024);

    hipMemsetAsync(ws + 70400000, 0, 800000, stream);  // cnt + cursor

    degree_k<<<6250, 256, 0, stream>>>(ei, cnt);
    scanA_k <<<98, 256, 0, stream>>>(cnt, bsum);
    scanB_k <<<1, 128, 0, stream>>>(bsum, bbase);
    scanC_k <<<98, 256, 0, stream>>>(cnt, bbase, offsets);
    fill_k  <<<6250, 256, 0, stream>>>(ei, offsets, cursor, csr);
    gemm1_k <<<1563, 256, 0, stream>>>(x, W1l, W1r, c1l, c1r);
    agg1_k  <<<25000, 256, 0, stream>>>(c1l, c1r, offsets, cnt, csr, b1, h);
    gemm2_k <<<1563, 256, 0, stream>>>(h, W2l, W2r, c2l, c2r);
    agg2_k  <<<12500, 256, 0, stream>>>(c2l, c2r, offsets, cnt, csr, b2, Wh, bh, out);
}

// Round 10
// 323.825 us; speedup vs baseline: 2.6702x; 1.3806x over previous
//
#include <hip/hip_runtime.h>
#include <hip/hip_bf16.h>

#define N_NODES 100000
#define N_EDGES 1600000
#define NBUCK   196      // ceil(100000/512) buckets of 512 dst nodes
#define BSHIFT  9
#define BCAP    12288    // entries/bucket: mean 8163, sigma~90 -> huge headroom

typedef __bf16 bf16x8 __attribute__((ext_vector_type(8)));
typedef float  f32x4  __attribute__((ext_vector_type(4)));

// Established facts:
//  - edge_index int32, float inputs fp32, OUTPUT fp32 (rounds 3-6).
//  - R6 865 (scatter atomics, WRITE=400MB) -> R7 757 (CSR) -> R8 578 (hier scan)
//    -> R9 447 (MFMA gemms + bf16 gather halves).
//  - R9 profile: fill_k 103us with WRITE=107MB (4B global scatter = full-line
//    amplification); degree_k ~90us (1.6M random global atomics, by accounting).
//  - R10: bucketed build. partition_k: LDS histo + per-bucket block reservation,
//    packed (d_local<<17|s) into per-bucket regions (clustered writes, L2-combined).
//    bucketcsr_k: per-bucket LDS count/scan -> cnt/offsets/csr, all local.

// ---------------------------------------------------------------------------
// partition: bucket edges by dst>>9 into bbuf, block-aggregated reservation.
__global__ __launch_bounds__(256) void partition_k(const int* __restrict__ ei,
                                                   int* __restrict__ gcur,
                                                   unsigned* __restrict__ bbuf) {
    __shared__ int hist[NBUCK];
    __shared__ int cur[NBUCK];
    int t = threadIdx.x;
    for (int i = t; i < NBUCK; i += 256) hist[i] = 0;
    __syncthreads();
    int base = blockIdx.x * 4096;                 // 391 blocks * 4096 >= E
    unsigned pk[16];
    int bk[16];
#pragma unroll
    for (int i = 0; i < 16; ++i) {
        int e = base + t + i * 256;               // coalesced
        if (e < N_EDGES) {
            int s = ei[e], d = ei[N_EDGES + e];
            int b = d >> BSHIFT;
            pk[i] = ((unsigned)(d & 511) << 17) | (unsigned)s;  // s < 2^17
            bk[i] = b;
            atomicAdd(&hist[b], 1);
        } else bk[i] = -1;
    }
    __syncthreads();
    for (int i = t; i < NBUCK; i += 256)
        cur[i] = atomicAdd(&gcur[i], hist[i]);    // reserve block's runs
    __syncthreads();
#pragma unroll
    for (int i = 0; i < 16; ++i) {
        if (bk[i] >= 0) {
            int pos = atomicAdd(&cur[bk[i]], 1);  // LDS cursor
            bbuf[(size_t)bk[i] * BCAP + pos] = pk[i];
        }
    }
}

// ---------------------------------------------------------------------------
// bucketcsr: per bucket -> per-node cnt, offsets (bucket-relative global), csr.
__global__ __launch_bounds__(256) void bucketcsr_k(const unsigned* __restrict__ bbuf,
                                                   const int* __restrict__ gcur,
                                                   int* __restrict__ cnt,
                                                   int* __restrict__ offsets,
                                                   int* __restrict__ csr) {
    __shared__ int lcnt[512];
    __shared__ int loff[512];
    __shared__ int lcur[512];
    __shared__ int ssum[256];
    int b = blockIdx.x, t = threadIdx.x;
    int m = gcur[b];                              // entries in this bucket
    const unsigned* src = bbuf + (size_t)b * BCAP;
    for (int i = t; i < 512; i += 256) lcnt[i] = 0;
    __syncthreads();
    for (int i = t; i < m; i += 256) atomicAdd(&lcnt[src[i] >> 17], 1);
    __syncthreads();
    // exclusive scan over 512 (2 elems/thread)
    int a0 = lcnt[2 * t], a1 = lcnt[2 * t + 1];
    ssum[t] = a0 + a1;
    __syncthreads();
    for (int off = 1; off < 256; off <<= 1) {
        int v = (t >= off) ? ssum[t - off] : 0;
        __syncthreads();
        ssum[t] += v;
        __syncthreads();
    }
    int ebase = (t == 0) ? 0 : ssum[t - 1];
    loff[2 * t] = ebase;
    loff[2 * t + 1] = ebase + a0;
    __syncthreads();
    for (int i = t; i < 512; i += 256) lcur[i] = loff[i];
    int nbase = b << BSHIFT;
    for (int i = t; i < 512; i += 256) {
        int n = nbase + i;
        if (n < N_NODES) {
            cnt[n] = lcnt[i];
            offsets[n] = b * BCAP + loff[i];      // csr keeps per-bucket gaps
        }
    }
    __syncthreads();
    // scatter src ids into the bucket's 48KB csr region (L2 write-combined)
    for (int i = t; i < m; i += 256) {
        unsigned p = src[i];
        int pos = atomicAdd(&lcur[p >> 17], 1);
        csr[(size_t)b * BCAP + pos] = (int)(p & 0x1FFFF);
    }
}

// ---------------------------------------------------------------------------
// GEMM1 (MFMA 16x16x32 bf16): [c1l | c1r] = x @ [W1_l | W1_r]
// c1l bf16 [N,64] (gathered by agg1), c1r fp32 [N,64] (root term, exact).
__global__ __launch_bounds__(256) void gemm1_k(const float* __restrict__ x,
                                               const float* __restrict__ W1l,
                                               const float* __restrict__ W1r,
                                               __bf16* __restrict__ c1l,
                                               float* __restrict__ c1r) {
    __shared__ __bf16 Bt[128 * 136];   // B^T[n][k], stride 136 = 128+8 pad
    int tid = threadIdx.x;
    for (int idx = tid; idx < 8192; idx += 256) {   // W is [128][64] each
        int k = idx >> 6, n = idx & 63;
        Bt[n * 136 + k]        = (__bf16)W1l[idx];
        Bt[(n + 64) * 136 + k] = (__bf16)W1r[idx];
    }
    __syncthreads();

    int lane = tid & 63, wave = tid >> 6;
    int mbase = blockIdx.x * 64 + wave * 16;        // 1563 blocks * 64 rows
    int col  = lane & 15;
    int kgrp = (lane >> 4) << 3;                    // 0,8,16,24
    int mrow = mbase + col;
    int mclamp = mrow < N_NODES ? mrow : N_NODES - 1;
    const float* arow = x + (size_t)mclamp * 128;

    f32x4 acc[8];
#pragma unroll
    for (int i = 0; i < 8; ++i) acc[i] = (f32x4){0.f, 0.f, 0.f, 0.f};

#pragma unroll
    for (int ks = 0; ks < 4; ++ks) {
        int kk = ks * 32 + kgrp;
        f32x4 a0 = *(const f32x4*)(arow + kk);
        f32x4 a1 = *(const f32x4*)(arow + kk + 4);
        bf16x8 a;
#pragma unroll
        for (int i = 0; i < 4; ++i) { a[i] = (__bf16)a0[i]; a[i + 4] = (__bf16)a1[i]; }
#pragma unroll
        for (int nt = 0; nt < 8; ++nt) {
            bf16x8 b = *(const bf16x8*)(Bt + (nt * 16 + col) * 136 + kk);
            acc[nt] = __builtin_amdgcn_mfma_f32_16x16x32_bf16(a, b, acc[nt], 0, 0, 0);
        }
    }

    // C/D: col = lane&15, row = (lane>>4)*4 + reg   [m89-verified]
    int r0 = mbase + ((lane >> 4) << 2);
#pragma unroll
    for (int r = 0; r < 4; ++r) {
        int m = r0 + r;
        if (m < N_NODES) {
#pragma unroll
            for (int nt = 0; nt < 4; ++nt)
                c1l[(size_t)m * 64 + nt * 16 + col] = (__bf16)acc[nt][r];
#pragma unroll
            for (int nt = 4; nt < 8; ++nt)
                c1r[(size_t)m * 64 + (nt - 4) * 16 + col] = acc[nt][r];
        }
    }
}

// ---------------------------------------------------------------------------
// agg1 (fused node1): wave per dst node, lane = feature (64).
// h[n] = relu( mean_gather(c1l) + c1r[n] + b1 )  -> bf16
__global__ __launch_bounds__(256) void agg1_k(const __bf16* __restrict__ c1l,
                                              const float* __restrict__ c1r,
                                              const int* __restrict__ offsets,
                                              const int* __restrict__ cnt,
                                              const int* __restrict__ csr,
                                              const float* __restrict__ b1,
                                              __bf16* __restrict__ h) {
    int n = blockIdx.x * 4 + (threadIdx.x >> 6);    // 25000*4 = 100000 exact
    int lane = threadIdx.x & 63;
    int beg = offsets[n], deg = cnt[n];
    int e = beg, end = beg + deg;
    float sum = 0.f;
    for (; e + 1 < end; e += 2) {                   // 2 outstanding gathers
        int s0 = csr[e], s1 = csr[e + 1];
        sum += (float)c1l[(size_t)s0 * 64 + lane];
        sum += (float)c1l[(size_t)s1 * 64 + lane];
    }
    if (e < end) sum += (float)c1l[(size_t)csr[e] * 64 + lane];
    float cf = deg > 0 ? (float)deg : 1.f;
    float v = sum / cf + c1r[(size_t)n * 64 + lane] + b1[lane];
    h[(size_t)n * 64 + lane] = (__bf16)(v > 0.f ? v : 0.f);
}

// ---------------------------------------------------------------------------
// GEMM2 (MFMA): [c2l | c2r] = h @ [W2_l | W2_r], h bf16 [N,64].
__global__ __launch_bounds__(256) void gemm2_k(const __bf16* __restrict__ h,
                                               const float* __restrict__ W2l,
                                               const float* __restrict__ W2r,
                                               __bf16* __restrict__ c2l,
                                               float* __restrict__ c2r) {
    __shared__ __bf16 Bt[64 * 72];   // stride 72 = 64+8 pad
    int tid = threadIdx.x;
    for (int idx = tid; idx < 2048; idx += 256) {   // W2 is [64][32] each
        int k = idx >> 5, n = idx & 31;
        Bt[n * 72 + k]        = (__bf16)W2l[idx];
        Bt[(n + 32) * 72 + k] = (__bf16)W2r[idx];
    }
    __syncthreads();

    int lane = tid & 63, wave = tid >> 6;
    int mbase = blockIdx.x * 64 + wave * 16;
    int col  = lane & 15;
    int kgrp = (lane >> 4) << 3;
    int mrow = mbase + col;
    int mclamp = mrow < N_NODES ? mrow : N_NODES - 1;
    const __bf16* arow = h + (size_t)mclamp * 64;

    f32x4 acc[4];
#pragma unroll
    for (int i = 0; i < 4; ++i) acc[i] = (f32x4){0.f, 0.f, 0.f, 0.f};

#pragma unroll
    for (int ks = 0; ks < 2; ++ks) {
        int kk = ks * 32 + kgrp;
        bf16x8 a = *(const bf16x8*)(arow + kk);
#pragma unroll
        for (int nt = 0; nt < 4; ++nt) {
            bf16x8 b = *(const bf16x8*)(Bt + (nt * 16 + col) * 72 + kk);
            acc[nt] = __builtin_amdgcn_mfma_f32_16x16x32_bf16(a, b, acc[nt], 0, 0, 0);
        }
    }

    int r0 = mbase + ((lane >> 4) << 2);
#pragma unroll
    for (int r = 0; r < 4; ++r) {
        int m = r0 + r;
        if (m < N_NODES) {
#pragma unroll
            for (int nt = 0; nt < 2; ++nt)
                c2l[(size_t)m * 32 + nt * 16 + col] = (__bf16)acc[nt][r];
#pragma unroll
            for (int nt = 2; nt < 4; ++nt)
                c2r[(size_t)m * 32 + (nt - 2) * 16 + col] = acc[nt][r];
        }
    }
}

// ---------------------------------------------------------------------------
// agg2 (fused final): half-wave per dst node, f = feature (32).
__global__ __launch_bounds__(256) void agg2_k(const __bf16* __restrict__ c2l,
                                              const float* __restrict__ c2r,
                                              const int* __restrict__ offsets,
                                              const int* __restrict__ cnt,
                                              const int* __restrict__ csr,
                                              const float* __restrict__ b2,
                                              const float* __restrict__ Wh,
                                              const float* __restrict__ bh,
                                              float* __restrict__ out) {
    int gwave = blockIdx.x * 4 + (threadIdx.x >> 6); // 12500*4 = 50000 waves
    int lane = threadIdx.x & 63;
    int f = lane & 31;
    int n = gwave * 2 + (lane >> 5);                 // 2 nodes/wave, exact
    int beg = offsets[n], deg = cnt[n];
    int e = beg, end = beg + deg;
    float sum = 0.f;
    for (; e + 1 < end; e += 2) {
        int s0 = csr[e], s1 = csr[e + 1];
        sum += (float)c2l[(size_t)s0 * 32 + f] + (float)c2l[(size_t)s1 * 32 + f];
    }
    if (e < end) sum += (float)c2l[(size_t)csr[e] * 32 + f];
    float cf = deg > 0 ? (float)deg : 1.f;
    float v = sum / cf + c2r[(size_t)n * 32 + f] + b2[f];
    v = v > 0.f ? v : 0.f;
    out[(size_t)n * 32 + f] = v;
    float r = v * Wh[f];
#pragma unroll
    for (int m = 16; m; m >>= 1) r += __shfl_xor(r, m, 64);  // stays in half-wave
    if (f == 0) out[(size_t)N_NODES * 32 + n] = r + bh[0];
}

// ---------------------------------------------------------------------------
extern "C" void kernel_launch(void* const* d_in, const int* in_sizes, int n_in,
                              void* d_out, int out_size, void* d_ws, size_t ws_size,
                              hipStream_t stream) {
    const float* x   = (const float*)d_in[0];
    const int*   ei  = (const int*)d_in[1];
    const float* W1l = (const float*)d_in[2];
    const float* b1  = (const float*)d_in[3];
    const float* W1r = (const float*)d_in[4];
    const float* W2l = (const float*)d_in[5];
    const float* b2  = (const float*)d_in[6];
    const float* W2r = (const float*)d_in[7];
    const float* Wh  = (const float*)d_in[8];
    const float* bh  = (const float*)d_in[9];
    float* out = (float*)d_out;

    // workspace layout (bytes):
    //   c1l     @ 0.0M     N*64*2 = 12,800,000  (bf16, gathered)
    //   c1r     @ 12.8M    N*64*4 = 25,600,000  (fp32 root)
    //   h       @ 38.4M    N*64*2 = 12,800,000  (bf16)
    //   c2l     @ 51.2M    N*32*2 =  6,400,000  (bf16, gathered)
    //   c2r     @ 57.6M    N*32*4 = 12,800,000  (fp32 root)
    //   cnt     @ 70.4M    N*4    =    400,000
    //   offsets @ 70.8M    N*4    =    400,000
    //   gcur    @ 71.2M    196*4  (pad 4096, zeroed)
    //   bbuf    @ 71.21M   196*12288*4 = 9,633,792
    //   csr     @ 80.85M   196*12288*4 = 9,633,792
    // total ~90.5 MB
    char* ws = (char*)d_ws;
    __bf16*   c1l     = (__bf16*)(ws);
    float*    c1r     = (float*)(ws + 12800000);
    __bf16*   h       = (__bf16*)(ws + 38400000);
    __bf16*   c2l     = (__bf16*)(ws + 51200000);
    float*    c2r     = (float*)(ws + 57600000);
    int*      cnt     = (int*)(ws + 70400000);
    int*      offsets = (int*)(ws + 70800000);
    int*      gcur    = (int*)(ws + 71200000);
    unsigned* bbuf    = (unsigned*)(ws + 71204096);
    int*      csr     = (int*)(ws + 80837888);

    hipMemsetAsync(gcur, 0, NBUCK * 4, stream);

    partition_k<<<391, 256, 0, stream>>>(ei, gcur, bbuf);
    bucketcsr_k<<<NBUCK, 256, 0, stream>>>(bbuf, gcur, cnt, offsets, csr);
    gemm1_k    <<<1563, 256, 0, stream>>>(x, W1l, W1r, c1l, c1r);
    agg1_k     <<<25000, 256, 0, stream>>>(c1l, c1r, offsets, cnt, csr, b1, h);
    gemm2_k    <<<1563, 256, 0, stream>>>(h, W2l, W2r, c2l, c2r);
    agg2_k     <<<12500, 256, 0, stream>>>(c2l, c2r, offsets, cnt, csr, b2, Wh, bh, out);
}

// Round 11
// 290.291 us; speedup vs baseline: 2.9787x; 1.1155x over previous
//
#include <hip/hip_runtime.h>
#include <hip/hip_bf16.h>

#define N_NODES 100000
#define N_EDGES 1600000
#define NBUCK   196      // ceil(100000/512) buckets of 512 dst nodes
#define BSHIFT  9
#define BCAP    12288    // entries/bucket: mean 8163 -> huge headroom

typedef __bf16 bf16x8 __attribute__((ext_vector_type(8)));
typedef __bf16 bf16x4 __attribute__((ext_vector_type(4)));
typedef float  f32x4  __attribute__((ext_vector_type(4)));

// Established facts:
//  - edge_index int32, float inputs fp32, OUTPUT fp32 (rounds 3-6).
//  - R6 865 -> R7 757 (CSR) -> R8 578 (hier scan) -> R9 447 (MFMA+bf16 halves)
//    -> R10 324 (bucketed build: partition+bucketcsr).
//  - R10 profile: agg1_k 93us latency-bound (VALUBusy 31%, 2B/lane gathers,
//    only 256B/wave in flight). R11: 8B bf16x4 gathers, 4-8 edges in flight.

// ---------------------------------------------------------------------------
// partition: bucket edges by dst>>9 into bbuf, block-aggregated reservation.
__global__ __launch_bounds__(256) void partition_k(const int* __restrict__ ei,
                                                   int* __restrict__ gcur,
                                                   unsigned* __restrict__ bbuf) {
    __shared__ int hist[NBUCK];
    __shared__ int cur[NBUCK];
    int t = threadIdx.x;
    for (int i = t; i < NBUCK; i += 256) hist[i] = 0;
    __syncthreads();
    int base = blockIdx.x * 4096;                 // 391 blocks * 4096 >= E
    unsigned pk[16];
    int bk[16];
#pragma unroll
    for (int i = 0; i < 16; ++i) {
        int e = base + t + i * 256;               // coalesced
        if (e < N_EDGES) {
            int s = ei[e], d = ei[N_EDGES + e];
            int b = d >> BSHIFT;
            pk[i] = ((unsigned)(d & 511) << 17) | (unsigned)s;  // s < 2^17
            bk[i] = b;
            atomicAdd(&hist[b], 1);
        } else bk[i] = -1;
    }
    __syncthreads();
    for (int i = t; i < NBUCK; i += 256)
        cur[i] = atomicAdd(&gcur[i], hist[i]);    // reserve block's runs
    __syncthreads();
#pragma unroll
    for (int i = 0; i < 16; ++i) {
        if (bk[i] >= 0) {
            int pos = atomicAdd(&cur[bk[i]], 1);  // LDS cursor
            bbuf[(size_t)bk[i] * BCAP + pos] = pk[i];
        }
    }
}

// ---------------------------------------------------------------------------
// bucketcsr: per bucket -> per-node cnt, offsets (bucket-relative global), csr.
__global__ __launch_bounds__(256) void bucketcsr_k(const unsigned* __restrict__ bbuf,
                                                   const int* __restrict__ gcur,
                                                   int* __restrict__ cnt,
                                                   int* __restrict__ offsets,
                                                   int* __restrict__ csr) {
    __shared__ int lcnt[512];
    __shared__ int loff[512];
    __shared__ int lcur[512];
    __shared__ int ssum[256];
    int b = blockIdx.x, t = threadIdx.x;
    int m = gcur[b];                              // entries in this bucket
    const unsigned* src = bbuf + (size_t)b * BCAP;
    for (int i = t; i < 512; i += 256) lcnt[i] = 0;
    __syncthreads();
    for (int i = t; i < m; i += 256) atomicAdd(&lcnt[src[i] >> 17], 1);
    __syncthreads();
    int a0 = lcnt[2 * t], a1 = lcnt[2 * t + 1];
    ssum[t] = a0 + a1;
    __syncthreads();
    for (int off = 1; off < 256; off <<= 1) {
        int v = (t >= off) ? ssum[t - off] : 0;
        __syncthreads();
        ssum[t] += v;
        __syncthreads();
    }
    int ebase = (t == 0) ? 0 : ssum[t - 1];
    loff[2 * t] = ebase;
    loff[2 * t + 1] = ebase + a0;
    __syncthreads();
    for (int i = t; i < 512; i += 256) lcur[i] = loff[i];
    int nbase = b << BSHIFT;
    for (int i = t; i < 512; i += 256) {
        int n = nbase + i;
        if (n < N_NODES) {
            cnt[n] = lcnt[i];
            offsets[n] = b * BCAP + loff[i];      // csr keeps per-bucket gaps
        }
    }
    __syncthreads();
    for (int i = t; i < m; i += 256) {
        unsigned p = src[i];
        int pos = atomicAdd(&lcur[p >> 17], 1);
        csr[(size_t)b * BCAP + pos] = (int)(p & 0x1FFFF);
    }
}

// ---------------------------------------------------------------------------
// GEMM1 (MFMA 16x16x32 bf16): [c1l | c1r] = x @ [W1_l | W1_r]
__global__ __launch_bounds__(256) void gemm1_k(const float* __restrict__ x,
                                               const float* __restrict__ W1l,
                                               const float* __restrict__ W1r,
                                               __bf16* __restrict__ c1l,
                                               float* __restrict__ c1r) {
    __shared__ __bf16 Bt[128 * 136];   // B^T[n][k], stride 136 = 128+8 pad
    int tid = threadIdx.x;
    for (int idx = tid; idx < 8192; idx += 256) {   // W is [128][64] each
        int k = idx >> 6, n = idx & 63;
        Bt[n * 136 + k]        = (__bf16)W1l[idx];
        Bt[(n + 64) * 136 + k] = (__bf16)W1r[idx];
    }
    __syncthreads();

    int lane = tid & 63, wave = tid >> 6;
    int mbase = blockIdx.x * 64 + wave * 16;        // 1563 blocks * 64 rows
    int col  = lane & 15;
    int kgrp = (lane >> 4) << 3;                    // 0,8,16,24
    int mrow = mbase + col;
    int mclamp = mrow < N_NODES ? mrow : N_NODES - 1;
    const float* arow = x + (size_t)mclamp * 128;

    f32x4 acc[8];
#pragma unroll
    for (int i = 0; i < 8; ++i) acc[i] = (f32x4){0.f, 0.f, 0.f, 0.f};

#pragma unroll
    for (int ks = 0; ks < 4; ++ks) {
        int kk = ks * 32 + kgrp;
        f32x4 a0 = *(const f32x4*)(arow + kk);
        f32x4 a1 = *(const f32x4*)(arow + kk + 4);
        bf16x8 a;
#pragma unroll
        for (int i = 0; i < 4; ++i) { a[i] = (__bf16)a0[i]; a[i + 4] = (__bf16)a1[i]; }
#pragma unroll
        for (int nt = 0; nt < 8; ++nt) {
            bf16x8 b = *(const bf16x8*)(Bt + (nt * 16 + col) * 136 + kk);
            acc[nt] = __builtin_amdgcn_mfma_f32_16x16x32_bf16(a, b, acc[nt], 0, 0, 0);
        }
    }

    // C/D: col = lane&15, row = (lane>>4)*4 + reg   [m89-verified]
    int r0 = mbase + ((lane >> 4) << 2);
#pragma unroll
    for (int r = 0; r < 4; ++r) {
        int m = r0 + r;
        if (m < N_NODES) {
#pragma unroll
            for (int nt = 0; nt < 4; ++nt)
                c1l[(size_t)m * 64 + nt * 16 + col] = (__bf16)acc[nt][r];
#pragma unroll
            for (int nt = 4; nt < 8; ++nt)
                c1r[(size_t)m * 64 + (nt - 4) * 16 + col] = acc[nt][r];
        }
    }
}

// ---------------------------------------------------------------------------
// agg1 v2: wave per dst node. lane = es(0..3)*16 + fl(0..15).
// Each lane gathers bf16x4 (8B) of feature block fl*4 for edge slot es;
// 4-deep unroll -> 16 edges & 4 outstanding loads per lane per iteration.
__global__ __launch_bounds__(256) void agg1_k(const __bf16* __restrict__ c1l,
                                              const float* __restrict__ c1r,
                                              const int* __restrict__ offsets,
                                              const int* __restrict__ cnt,
                                              const int* __restrict__ csr,
                                              const float* __restrict__ b1,
                                              __bf16* __restrict__ h) {
    int n = blockIdx.x * 4 + (threadIdx.x >> 6);    // 25000*4 = 100000 exact
    int lane = threadIdx.x & 63;
    int es = lane >> 4;                             // edge slot 0..3
    int f4 = (lane & 15) << 2;                      // feature base
    int beg = offsets[n], deg = cnt[n];
    int end = beg + deg;
    f32x4 sum = {0.f, 0.f, 0.f, 0.f};
    for (int e = beg; e < end; e += 16) {
#pragma unroll
        for (int u = 0; u < 4; ++u) {
            int i = e + u * 4 + es;
            if (i < end) {
                int s = csr[i];
                bf16x4 v = *(const bf16x4*)(c1l + (size_t)s * 64 + f4);
#pragma unroll
                for (int j = 0; j < 4; ++j) sum[j] += (float)v[j];
            }
        }
    }
#pragma unroll
    for (int j = 0; j < 4; ++j) {                   // reduce across es (bits 4,5)
        sum[j] += __shfl_xor(sum[j], 16, 64);
        sum[j] += __shfl_xor(sum[j], 32, 64);
    }
    if (es == 0) {
        float cf = deg > 0 ? (float)deg : 1.f;
        bf16x4 o;
#pragma unroll
        for (int j = 0; j < 4; ++j) {
            float v = sum[j] / cf + c1r[(size_t)n * 64 + f4 + j] + b1[f4 + j];
            o[j] = (__bf16)(v > 0.f ? v : 0.f);
        }
        *(bf16x4*)(h + (size_t)n * 64 + f4) = o;
    }
}

// ---------------------------------------------------------------------------
// GEMM2 (MFMA): [c2l | c2r] = h @ [W2_l | W2_r], h bf16 [N,64].
__global__ __launch_bounds__(256) void gemm2_k(const __bf16* __restrict__ h,
                                               const float* __restrict__ W2l,
                                               const float* __restrict__ W2r,
                                               __bf16* __restrict__ c2l,
                                               float* __restrict__ c2r) {
    __shared__ __bf16 Bt[64 * 72];   // stride 72 = 64+8 pad
    int tid = threadIdx.x;
    for (int idx = tid; idx < 2048; idx += 256) {   // W2 is [64][32] each
        int k = idx >> 5, n = idx & 31;
        Bt[n * 72 + k]        = (__bf16)W2l[idx];
        Bt[(n + 32) * 72 + k] = (__bf16)W2r[idx];
    }
    __syncthreads();

    int lane = tid & 63, wave = tid >> 6;
    int mbase = blockIdx.x * 64 + wave * 16;
    int col  = lane & 15;
    int kgrp = (lane >> 4) << 3;
    int mrow = mbase + col;
    int mclamp = mrow < N_NODES ? mrow : N_NODES - 1;
    const __bf16* arow = h + (size_t)mclamp * 64;

    f32x4 acc[4];
#pragma unroll
    for (int i = 0; i < 4; ++i) acc[i] = (f32x4){0.f, 0.f, 0.f, 0.f};

#pragma unroll
    for (int ks = 0; ks < 2; ++ks) {
        int kk = ks * 32 + kgrp;
        bf16x8 a = *(const bf16x8*)(arow + kk);
#pragma unroll
        for (int nt = 0; nt < 4; ++nt) {
            bf16x8 b = *(const bf16x8*)(Bt + (nt * 16 + col) * 72 + kk);
            acc[nt] = __builtin_amdgcn_mfma_f32_16x16x32_bf16(a, b, acc[nt], 0, 0, 0);
        }
    }

    int r0 = mbase + ((lane >> 4) << 2);
#pragma unroll
    for (int r = 0; r < 4; ++r) {
        int m = r0 + r;
        if (m < N_NODES) {
#pragma unroll
            for (int nt = 0; nt < 2; ++nt)
                c2l[(size_t)m * 32 + nt * 16 + col] = (__bf16)acc[nt][r];
#pragma unroll
            for (int nt = 2; nt < 4; ++nt)
                c2r[(size_t)m * 32 + (nt - 2) * 16 + col] = acc[nt][r];
        }
    }
}

// ---------------------------------------------------------------------------
// agg2 v2 (fused final): wave per dst node. lane = es(0..7)*8 + fl(0..7).
// bf16x4 gathers; 2-deep unroll -> 16 edges per iteration.
__global__ __launch_bounds__(256) void agg2_k(const __bf16* __restrict__ c2l,
                                              const float* __restrict__ c2r,
                                              const int* __restrict__ offsets,
                                              const int* __restrict__ cnt,
                                              const int* __restrict__ csr,
                                              const float* __restrict__ b2,
                                              const float* __restrict__ Wh,
                                              const float* __restrict__ bh,
                                              float* __restrict__ out) {
    int n = blockIdx.x * 4 + (threadIdx.x >> 6);    // 25000*4 = 100000 exact
    int lane = threadIdx.x & 63;
    int es = lane >> 3;                             // edge slot 0..7
    int f4 = (lane & 7) << 2;                       // feature base 0..28
    int beg = offsets[n], deg = cnt[n];
    int end = beg + deg;
    f32x4 sum = {0.f, 0.f, 0.f, 0.f};
    for (int e = beg; e < end; e += 16) {
#pragma unroll
        for (int u = 0; u < 2; ++u) {
            int i = e + u * 8 + es;
            if (i < end) {
                int s = csr[i];
                bf16x4 v = *(const bf16x4*)(c2l + (size_t)s * 32 + f4);
#pragma unroll
                for (int j = 0; j < 4; ++j) sum[j] += (float)v[j];
            }
        }
    }
#pragma unroll
    for (int j = 0; j < 4; ++j) {                   // reduce across es (bits 3,4,5)
        sum[j] += __shfl_xor(sum[j], 8, 64);
        sum[j] += __shfl_xor(sum[j], 16, 64);
        sum[j] += __shfl_xor(sum[j], 32, 64);
    }
    if (es == 0) {                                  // lanes 0..7
        float cf = deg > 0 ? (float)deg : 1.f;
        f32x4 o;
        float r = 0.f;
#pragma unroll
        for (int j = 0; j < 4; ++j) {
            float v = sum[j] / cf + c2r[(size_t)n * 32 + f4 + j] + b2[f4 + j];
            v = v > 0.f ? v : 0.f;
            o[j] = v;
            r += v * Wh[f4 + j];
        }
        *(f32x4*)(out + (size_t)n * 32 + f4) = o;
        r += __shfl_xor(r, 1, 64);                  // reduce within lanes 0..7
        r += __shfl_xor(r, 2, 64);
        r += __shfl_xor(r, 4, 64);
        if (f4 == 0) out[(size_t)N_NODES * 32 + n] = r + bh[0];
    }
}

// ---------------------------------------------------------------------------
extern "C" void kernel_launch(void* const* d_in, const int* in_sizes, int n_in,
                              void* d_out, int out_size, void* d_ws, size_t ws_size,
                              hipStream_t stream) {
    const float* x   = (const float*)d_in[0];
    const int*   ei  = (const int*)d_in[1];
    const float* W1l = (const float*)d_in[2];
    const float* b1  = (const float*)d_in[3];
    const float* W1r = (const float*)d_in[4];
    const float* W2l = (const float*)d_in[5];
    const float* b2  = (const float*)d_in[6];
    const float* W2r = (const float*)d_in[7];
    const float* Wh  = (const float*)d_in[8];
    const float* bh  = (const float*)d_in[9];
    float* out = (float*)d_out;

    // workspace layout (bytes): c1l 12.8M | c1r 25.6M | h 12.8M | c2l 6.4M |
    // c2r 12.8M | cnt 0.4M | offsets 0.4M | gcur pad | bbuf 9.6M | csr 9.6M
    char* ws = (char*)d_ws;
    __bf16*   c1l     = (__bf16*)(ws);
    float*    c1r     = (float*)(ws + 12800000);
    __bf16*   h       = (__bf16*)(ws + 38400000);
    __bf16*   c2l     = (__bf16*)(ws + 51200000);
    float*    c2r     = (float*)(ws + 57600000);
    int*      cnt     = (int*)(ws + 70400000);
    int*      offsets = (int*)(ws + 70800000);
    int*      gcur    = (int*)(ws + 71200000);
    unsigned* bbuf    = (unsigned*)(ws + 71204096);
    int*      csr     = (int*)(ws + 80837888);

    hipMemsetAsync(gcur, 0, NBUCK * 4, stream);

    partition_k<<<391, 256, 0, stream>>>(ei, gcur, bbuf);
    bucketcsr_k<<<NBUCK, 256, 0, stream>>>(bbuf, gcur, cnt, offsets, csr);
    gemm1_k    <<<1563, 256, 0, stream>>>(x, W1l, W1r, c1l, c1r);
    agg1_k     <<<25000, 256, 0, stream>>>(c1l, c1r, offsets, cnt, csr, b1, h);
    gemm2_k    <<<1563, 256, 0, stream>>>(h, W2l, W2r, c2l, c2r);
    agg2_k     <<<25000, 256, 0, stream>>>(c2l, c2r, offsets, cnt, csr, b2, Wh, bh, out);
}

// Round 12
// 273.119 us; speedup vs baseline: 3.1660x; 1.0629x over previous
//
#include <hip/hip_runtime.h>
#include <hip/hip_bf16.h>

#define N_NODES 100000
#define N_EDGES 1600000
#define NBUCK   196      // ceil(100000/512) buckets of 512 dst nodes
#define BSHIFT  9
#define BCAP    12288    // entries/bucket: mean 8163 -> huge headroom

typedef __bf16 bf16x8 __attribute__((ext_vector_type(8)));
typedef float  f32x4  __attribute__((ext_vector_type(4)));
typedef float  f32x2  __attribute__((ext_vector_type(2)));

// Established facts:
//  - edge_index int32, float inputs fp32, OUTPUT fp32 (rounds 3-6).
//  - R6 865 -> R7 757 (CSR) -> R8 578 (hier scan) -> R9 447 (MFMA+bf16 halves)
//    -> R10 324 (bucketed build) -> R11 290 (8B gathers).
//  - R11: agg1 66us, FETCH pinned at 97MB -> L2-miss-path bound (12.8MB c1l
//    vs 4MiB/XCD L2, ~50% hit). R12: fp8 e4m3 gather halves (c1l 6.4MB,
//    c2l 3.2MB ~L2-resident); HW cvt_pk_f32_fp8 decode. Roots stay fp32.

__device__ inline unsigned char enc_fp8(float v) {
    return (unsigned char)(__builtin_amdgcn_cvt_pk_fp8_f32(v, v, 0, 0) & 0xFF);
}

// ---------------------------------------------------------------------------
// partition: bucket edges by dst>>9 into bbuf, block-aggregated reservation.
__global__ __launch_bounds__(256) void partition_k(const int* __restrict__ ei,
                                                   int* __restrict__ gcur,
                                                   unsigned* __restrict__ bbuf) {
    __shared__ int hist[NBUCK];
    __shared__ int cur[NBUCK];
    int t = threadIdx.x;
    for (int i = t; i < NBUCK; i += 256) hist[i] = 0;
    __syncthreads();
    int base = blockIdx.x * 4096;                 // 391 blocks * 4096 >= E
    unsigned pk[16];
    int bk[16];
#pragma unroll
    for (int i = 0; i < 16; ++i) {
        int e = base + t + i * 256;               // coalesced
        if (e < N_EDGES) {
            int s = ei[e], d = ei[N_EDGES + e];
            int b = d >> BSHIFT;
            pk[i] = ((unsigned)(d & 511) << 17) | (unsigned)s;  // s < 2^17
            bk[i] = b;
            atomicAdd(&hist[b], 1);
        } else bk[i] = -1;
    }
    __syncthreads();
    for (int i = t; i < NBUCK; i += 256)
        cur[i] = atomicAdd(&gcur[i], hist[i]);    // reserve block's runs
    __syncthreads();
#pragma unroll
    for (int i = 0; i < 16; ++i) {
        if (bk[i] >= 0) {
            int pos = atomicAdd(&cur[bk[i]], 1);  // LDS cursor
            bbuf[(size_t)bk[i] * BCAP + pos] = pk[i];
        }
    }
}

// ---------------------------------------------------------------------------
// bucketcsr: per bucket -> per-node cnt, offsets (bucket-relative global), csr.
__global__ __launch_bounds__(256) void bucketcsr_k(const unsigned* __restrict__ bbuf,
                                                   const int* __restrict__ gcur,
                                                   int* __restrict__ cnt,
                                                   int* __restrict__ offsets,
                                                   int* __restrict__ csr) {
    __shared__ int lcnt[512];
    __shared__ int loff[512];
    __shared__ int lcur[512];
    __shared__ int ssum[256];
    int b = blockIdx.x, t = threadIdx.x;
    int m = gcur[b];                              // entries in this bucket
    const unsigned* src = bbuf + (size_t)b * BCAP;
    for (int i = t; i < 512; i += 256) lcnt[i] = 0;
    __syncthreads();
    for (int i = t; i < m; i += 256) atomicAdd(&lcnt[src[i] >> 17], 1);
    __syncthreads();
    int a0 = lcnt[2 * t], a1 = lcnt[2 * t + 1];
    ssum[t] = a0 + a1;
    __syncthreads();
    for (int off = 1; off < 256; off <<= 1) {
        int v = (t >= off) ? ssum[t - off] : 0;
        __syncthreads();
        ssum[t] += v;
        __syncthreads();
    }
    int ebase = (t == 0) ? 0 : ssum[t - 1];
    loff[2 * t] = ebase;
    loff[2 * t + 1] = ebase + a0;
    __syncthreads();
    for (int i = t; i < 512; i += 256) lcur[i] = loff[i];
    int nbase = b << BSHIFT;
    for (int i = t; i < 512; i += 256) {
        int n = nbase + i;
        if (n < N_NODES) {
            cnt[n] = lcnt[i];
            offsets[n] = b * BCAP + loff[i];      // csr keeps per-bucket gaps
        }
    }
    __syncthreads();
    for (int i = t; i < m; i += 256) {
        unsigned p = src[i];
        int pos = atomicAdd(&lcur[p >> 17], 1);
        csr[(size_t)b * BCAP + pos] = (int)(p & 0x1FFFF);
    }
}

// ---------------------------------------------------------------------------
// GEMM1 (MFMA 16x16x32 bf16): [c1l | c1r] = x @ [W1_l | W1_r]
// c1l fp8-e4m3 [N,64] (gathered), c1r fp32 [N,64] (root, exact).
__global__ __launch_bounds__(256) void gemm1_k(const float* __restrict__ x,
                                               const float* __restrict__ W1l,
                                               const float* __restrict__ W1r,
                                               unsigned char* __restrict__ c1l,
                                               float* __restrict__ c1r) {
    __shared__ __bf16 Bt[128 * 136];   // B^T[n][k], stride 136 = 128+8 pad
    int tid = threadIdx.x;
    for (int idx = tid; idx < 8192; idx += 256) {   // W is [128][64] each
        int k = idx >> 6, n = idx & 63;
        Bt[n * 136 + k]        = (__bf16)W1l[idx];
        Bt[(n + 64) * 136 + k] = (__bf16)W1r[idx];
    }
    __syncthreads();

    int lane = tid & 63, wave = tid >> 6;
    int mbase = blockIdx.x * 64 + wave * 16;        // 1563 blocks * 64 rows
    int col  = lane & 15;
    int kgrp = (lane >> 4) << 3;                    // 0,8,16,24
    int mrow = mbase + col;
    int mclamp = mrow < N_NODES ? mrow : N_NODES - 1;
    const float* arow = x + (size_t)mclamp * 128;

    f32x4 acc[8];
#pragma unroll
    for (int i = 0; i < 8; ++i) acc[i] = (f32x4){0.f, 0.f, 0.f, 0.f};

#pragma unroll
    for (int ks = 0; ks < 4; ++ks) {
        int kk = ks * 32 + kgrp;
        f32x4 a0 = *(const f32x4*)(arow + kk);
        f32x4 a1 = *(const f32x4*)(arow + kk + 4);
        bf16x8 a;
#pragma unroll
        for (int i = 0; i < 4; ++i) { a[i] = (__bf16)a0[i]; a[i + 4] = (__bf16)a1[i]; }
#pragma unroll
        for (int nt = 0; nt < 8; ++nt) {
            bf16x8 b = *(const bf16x8*)(Bt + (nt * 16 + col) * 136 + kk);
            acc[nt] = __builtin_amdgcn_mfma_f32_16x16x32_bf16(a, b, acc[nt], 0, 0, 0);
        }
    }

    // C/D: col = lane&15, row = (lane>>4)*4 + reg   [m89-verified]
    int r0 = mbase + ((lane >> 4) << 2);
#pragma unroll
    for (int r = 0; r < 4; ++r) {
        int m = r0 + r;
        if (m < N_NODES) {
#pragma unroll
            for (int nt = 0; nt < 4; ++nt)
                c1l[(size_t)m * 64 + nt * 16 + col] = enc_fp8(acc[nt][r]);
#pragma unroll
            for (int nt = 4; nt < 8; ++nt)
                c1r[(size_t)m * 64 + (nt - 4) * 16 + col] = acc[nt][r];
        }
    }
}

// ---------------------------------------------------------------------------
// agg1 v3 (fp8): wave per dst node. lane = es(0..7)*8 + fl(0..7).
// Each lane gathers 8B = 8 fp8 features for edge slot es; unroll 4 ->
// 32 edges/iter, 4 outstanding loads/lane. HW cvt_pk_f32_fp8 decode.
__global__ __launch_bounds__(256) void agg1_k(const unsigned char* __restrict__ c1l,
                                              const float* __restrict__ c1r,
                                              const int* __restrict__ offsets,
                                              const int* __restrict__ cnt,
                                              const int* __restrict__ csr,
                                              const float* __restrict__ b1,
                                              __bf16* __restrict__ h) {
    int n = blockIdx.x * 4 + (threadIdx.x >> 6);    // 25000*4 = 100000 exact
    int lane = threadIdx.x & 63;
    int es = lane >> 3;                             // edge slot 0..7
    int f8b = (lane & 7) << 3;                      // feature base 0..56
    int beg = offsets[n], deg = cnt[n];
    int end = beg + deg;
    float sum[8];
#pragma unroll
    for (int j = 0; j < 8; ++j) sum[j] = 0.f;
    for (int e = beg; e < end; e += 32) {
#pragma unroll
        for (int u = 0; u < 4; ++u) {
            int i = e + u * 8 + es;
            if (i < end) {
                int s = csr[i];
                uint2 w = *(const uint2*)(c1l + (size_t)s * 64 + f8b);
                f32x2 p0 = __builtin_amdgcn_cvt_pk_f32_fp8(w.x, 0);
                f32x2 p1 = __builtin_amdgcn_cvt_pk_f32_fp8(w.x, 1);
                f32x2 p2 = __builtin_amdgcn_cvt_pk_f32_fp8(w.y, 0);
                f32x2 p3 = __builtin_amdgcn_cvt_pk_f32_fp8(w.y, 1);
                sum[0] += p0[0]; sum[1] += p0[1];
                sum[2] += p1[0]; sum[3] += p1[1];
                sum[4] += p2[0]; sum[5] += p2[1];
                sum[6] += p3[0]; sum[7] += p3[1];
            }
        }
    }
#pragma unroll
    for (int j = 0; j < 8; ++j) {                   // reduce across es (bits 3,4,5)
        sum[j] += __shfl_xor(sum[j], 8, 64);
        sum[j] += __shfl_xor(sum[j], 16, 64);
        sum[j] += __shfl_xor(sum[j], 32, 64);
    }
    if (es == 0) {                                  // lanes 0..7
        float cf = deg > 0 ? (float)deg : 1.f;
        bf16x8 o;
#pragma unroll
        for (int j = 0; j < 8; ++j) {
            float v = sum[j] / cf + c1r[(size_t)n * 64 + f8b + j] + b1[f8b + j];
            o[j] = (__bf16)(v > 0.f ? v : 0.f);
        }
        *(bf16x8*)(h + (size_t)n * 64 + f8b) = o;
    }
}

// ---------------------------------------------------------------------------
// GEMM2 (MFMA): [c2l | c2r] = h @ [W2_l | W2_r], h bf16 [N,64].
// c2l fp8-e4m3 [N,32], c2r fp32 [N,32].
__global__ __launch_bounds__(256) void gemm2_k(const __bf16* __restrict__ h,
                                               const float* __restrict__ W2l,
                                               const float* __restrict__ W2r,
                                               unsigned char* __restrict__ c2l,
                                               float* __restrict__ c2r) {
    __shared__ __bf16 Bt[64 * 72];   // stride 72 = 64+8 pad
    int tid = threadIdx.x;
    for (int idx = tid; idx < 2048; idx += 256) {   // W2 is [64][32] each
        int k = idx >> 5, n = idx & 31;
        Bt[n * 72 + k]        = (__bf16)W2l[idx];
        Bt[(n + 32) * 72 + k] = (__bf16)W2r[idx];
    }
    __syncthreads();

    int lane = tid & 63, wave = tid >> 6;
    int mbase = blockIdx.x * 64 + wave * 16;
    int col  = lane & 15;
    int kgrp = (lane >> 4) << 3;
    int mrow = mbase + col;
    int mclamp = mrow < N_NODES ? mrow : N_NODES - 1;
    const __bf16* arow = h + (size_t)mclamp * 64;

    f32x4 acc[4];
#pragma unroll
    for (int i = 0; i < 4; ++i) acc[i] = (f32x4){0.f, 0.f, 0.f, 0.f};

#pragma unroll
    for (int ks = 0; ks < 2; ++ks) {
        int kk = ks * 32 + kgrp;
        bf16x8 a = *(const bf16x8*)(arow + kk);
#pragma unroll
        for (int nt = 0; nt < 4; ++nt) {
            bf16x8 b = *(const bf16x8*)(Bt + (nt * 16 + col) * 72 + kk);
            acc[nt] = __builtin_amdgcn_mfma_f32_16x16x32_bf16(a, b, acc[nt], 0, 0, 0);
        }
    }

    int r0 = mbase + ((lane >> 4) << 2);
#pragma unroll
    for (int r = 0; r < 4; ++r) {
        int m = r0 + r;
        if (m < N_NODES) {
#pragma unroll
            for (int nt = 0; nt < 2; ++nt)
                c2l[(size_t)m * 32 + nt * 16 + col] = enc_fp8(acc[nt][r]);
#pragma unroll
            for (int nt = 2; nt < 4; ++nt)
                c2r[(size_t)m * 32 + (nt - 2) * 16 + col] = acc[nt][r];
        }
    }
}

// ---------------------------------------------------------------------------
// agg2 v3 (fp8, fused final): wave per dst node. lane = es(0..15)*4 + fl(0..3).
// 8B = 8 fp8 features/lane; unroll 2 -> 32 edges/iter.
__global__ __launch_bounds__(256) void agg2_k(const unsigned char* __restrict__ c2l,
                                              const float* __restrict__ c2r,
                                              const int* __restrict__ offsets,
                                              const int* __restrict__ cnt,
                                              const int* __restrict__ csr,
                                              const float* __restrict__ b2,
                                              const float* __restrict__ Wh,
                                              const float* __restrict__ bh,
                                              float* __restrict__ out) {
    int n = blockIdx.x * 4 + (threadIdx.x >> 6);    // 25000*4 = 100000 exact
    int lane = threadIdx.x & 63;
    int es = lane >> 2;                             // edge slot 0..15
    int f8b = (lane & 3) << 3;                      // feature base 0,8,16,24
    int beg = offsets[n], deg = cnt[n];
    int end = beg + deg;
    float sum[8];
#pragma unroll
    for (int j = 0; j < 8; ++j) sum[j] = 0.f;
    for (int e = beg; e < end; e += 32) {
#pragma unroll
        for (int u = 0; u < 2; ++u) {
            int i = e + u * 16 + es;
            if (i < end) {
                int s = csr[i];
                uint2 w = *(const uint2*)(c2l + (size_t)s * 32 + f8b);
                f32x2 p0 = __builtin_amdgcn_cvt_pk_f32_fp8(w.x, 0);
                f32x2 p1 = __builtin_amdgcn_cvt_pk_f32_fp8(w.x, 1);
                f32x2 p2 = __builtin_amdgcn_cvt_pk_f32_fp8(w.y, 0);
                f32x2 p3 = __builtin_amdgcn_cvt_pk_f32_fp8(w.y, 1);
                sum[0] += p0[0]; sum[1] += p0[1];
                sum[2] += p1[0]; sum[3] += p1[1];
                sum[4] += p2[0]; sum[5] += p2[1];
                sum[6] += p3[0]; sum[7] += p3[1];
            }
        }
    }
#pragma unroll
    for (int j = 0; j < 8; ++j) {                   // reduce across es (bits 2..5)
        sum[j] += __shfl_xor(sum[j], 4, 64);
        sum[j] += __shfl_xor(sum[j], 8, 64);
        sum[j] += __shfl_xor(sum[j], 16, 64);
        sum[j] += __shfl_xor(sum[j], 32, 64);
    }
    if (es == 0) {                                  // lanes 0..3
        float cf = deg > 0 ? (float)deg : 1.f;
        float r = 0.f;
        f32x4 o0, o1;
#pragma unroll
        for (int j = 0; j < 8; ++j) {
            float v = sum[j] / cf + c2r[(size_t)n * 32 + f8b + j] + b2[f8b + j];
            v = v > 0.f ? v : 0.f;
            if (j < 4) o0[j] = v; else o1[j - 4] = v;
            r += v * Wh[f8b + j];
        }
        *(f32x4*)(out + (size_t)n * 32 + f8b) = o0;
        *(f32x4*)(out + (size_t)n * 32 + f8b + 4) = o1;
        r += __shfl_xor(r, 1, 64);                  // reduce lanes 0..3
        r += __shfl_xor(r, 2, 64);
        if (lane == 0) out[(size_t)N_NODES * 32 + n] = r + bh[0];
    }
}

// ---------------------------------------------------------------------------
extern "C" void kernel_launch(void* const* d_in, const int* in_sizes, int n_in,
                              void* d_out, int out_size, void* d_ws, size_t ws_size,
                              hipStream_t stream) {
    const float* x   = (const float*)d_in[0];
    const int*   ei  = (const int*)d_in[1];
    const float* W1l = (const float*)d_in[2];
    const float* b1  = (const float*)d_in[3];
    const float* W1r = (const float*)d_in[4];
    const float* W2l = (const float*)d_in[5];
    const float* b2  = (const float*)d_in[6];
    const float* W2r = (const float*)d_in[7];
    const float* Wh  = (const float*)d_in[8];
    const float* bh  = (const float*)d_in[9];
    float* out = (float*)d_out;

    // workspace layout (bytes):
    //   c1l  @ 0          N*64*1 =  6,400,000  (fp8, gathered)
    //   c1r  @ 6.4M       N*64*4 = 25,600,000  (fp32 root)
    //   h    @ 32.0M      N*64*2 = 12,800,000  (bf16)
    //   c2l  @ 44.8M      N*32*1 =  3,200,000  (fp8, gathered)
    //   c2r  @ 48.0M      N*32*4 = 12,800,000  (fp32 root)
    //   cnt  @ 60.8M      N*4    =    400,000
    //   offs @ 61.2M      N*4    =    400,000
    //   gcur @ 61.6M      (pad 4096, zeroed)
    //   bbuf @ 61.604M    196*12288*4 = 9,633,792
    //   csr  @ 71.238M    196*12288*4 = 9,633,792
    char* ws = (char*)d_ws;
    unsigned char* c1l = (unsigned char*)(ws);
    float*    c1r     = (float*)(ws + 6400000);
    __bf16*   h       = (__bf16*)(ws + 32000000);
    unsigned char* c2l = (unsigned char*)(ws + 44800000);
    float*    c2r     = (float*)(ws + 48000000);
    int*      cnt     = (int*)(ws + 60800000);
    int*      offsets = (int*)(ws + 61200000);
    int*      gcur    = (int*)(ws + 61600000);
    unsigned* bbuf    = (unsigned*)(ws + 61604096);
    int*      csr     = (int*)(ws + 71237888);

    hipMemsetAsync(gcur, 0, NBUCK * 4, stream);

    partition_k<<<391, 256, 0, stream>>>(ei, gcur, bbuf);
    bucketcsr_k<<<NBUCK, 256, 0, stream>>>(bbuf, gcur, cnt, offsets, csr);
    gemm1_k    <<<1563, 256, 0, stream>>>(x, W1l, W1r, c1l, c1r);
    agg1_k     <<<25000, 256, 0, stream>>>(c1l, c1r, offsets, cnt, csr, b1, h);
    gemm2_k    <<<1563, 256, 0, stream>>>(h, W2l, W2r, c2l, c2r);
    agg2_k     <<<25000, 256, 0, stream>>>(c2l, c2r, offsets, cnt, csr, b2, Wh, bh, out);
}

// Round 13
// 236.108 us; speedup vs baseline: 3.6623x; 1.1568x over previous
//
#include <hip/hip_runtime.h>
#include <hip/hip_bf16.h>

#define N_NODES 100000
#define N_EDGES 1600000
#define NBUCK   196      // ceil(100000/512) buckets of 512 dst nodes
#define BSHIFT  9
#define BCAP    12288    // entries/bucket: mean 8163 -> huge headroom

typedef __bf16 bf16x8 __attribute__((ext_vector_type(8)));
typedef float  f32x4  __attribute__((ext_vector_type(4)));
typedef float  f32x2  __attribute__((ext_vector_type(2)));

// Established facts:
//  - edge_index int32, float inputs fp32, OUTPUT fp32 (rounds 3-6).
//  - R6 865 -> R7 757 (CSR) -> R8 578 (hier scan) -> R9 447 (MFMA+bf16 halves)
//    -> R10 324 (bucketed build) -> R11 290 (8B gathers) -> R12 273 (fp8 halves).
//  - R12: agg1 54us, VALUBusy 62% -> per-WAVE overhead (shfl reduce + prologue,
//    100K waves) dominates VALU, not per-edge work. R13: 8 nodes/wave in agg1
//    (8 lanes/node, lane-private sums, no reduce), 16 nodes/wave in agg2;
//    c1r -> bf16 (cuts 25.6MB traffic; error diluted through layer 2).

__device__ inline unsigned char enc_fp8(float v) {
    return (unsigned char)(__builtin_amdgcn_cvt_pk_fp8_f32(v, v, 0, 0) & 0xFF);
}

// ---------------------------------------------------------------------------
// partition: bucket edges by dst>>9 into bbuf, block-aggregated reservation.
__global__ __launch_bounds__(256) void partition_k(const int* __restrict__ ei,
                                                   int* __restrict__ gcur,
                                                   unsigned* __restrict__ bbuf) {
    __shared__ int hist[NBUCK];
    __shared__ int cur[NBUCK];
    int t = threadIdx.x;
    for (int i = t; i < NBUCK; i += 256) hist[i] = 0;
    __syncthreads();
    int base = blockIdx.x * 4096;                 // 391 blocks * 4096 >= E
    unsigned pk[16];
    int bk[16];
#pragma unroll
    for (int i = 0; i < 16; ++i) {
        int e = base + t + i * 256;               // coalesced
        if (e < N_EDGES) {
            int s = ei[e], d = ei[N_EDGES + e];
            int b = d >> BSHIFT;
            pk[i] = ((unsigned)(d & 511) << 17) | (unsigned)s;  // s < 2^17
            bk[i] = b;
            atomicAdd(&hist[b], 1);
        } else bk[i] = -1;
    }
    __syncthreads();
    for (int i = t; i < NBUCK; i += 256)
        cur[i] = atomicAdd(&gcur[i], hist[i]);    // reserve block's runs
    __syncthreads();
#pragma unroll
    for (int i = 0; i < 16; ++i) {
        if (bk[i] >= 0) {
            int pos = atomicAdd(&cur[bk[i]], 1);  // LDS cursor
            bbuf[(size_t)bk[i] * BCAP + pos] = pk[i];
        }
    }
}

// ---------------------------------------------------------------------------
// bucketcsr: per bucket -> per-node cnt, offsets (bucket-relative global), csr.
__global__ __launch_bounds__(256) void bucketcsr_k(const unsigned* __restrict__ bbuf,
                                                   const int* __restrict__ gcur,
                                                   int* __restrict__ cnt,
                                                   int* __restrict__ offsets,
                                                   int* __restrict__ csr) {
    __shared__ int lcnt[512];
    __shared__ int loff[512];
    __shared__ int lcur[512];
    __shared__ int ssum[256];
    int b = blockIdx.x, t = threadIdx.x;
    int m = gcur[b];                              // entries in this bucket
    const unsigned* src = bbuf + (size_t)b * BCAP;
    for (int i = t; i < 512; i += 256) lcnt[i] = 0;
    __syncthreads();
    for (int i = t; i < m; i += 256) atomicAdd(&lcnt[src[i] >> 17], 1);
    __syncthreads();
    int a0 = lcnt[2 * t], a1 = lcnt[2 * t + 1];
    ssum[t] = a0 + a1;
    __syncthreads();
    for (int off = 1; off < 256; off <<= 1) {
        int v = (t >= off) ? ssum[t - off] : 0;
        __syncthreads();
        ssum[t] += v;
        __syncthreads();
    }
    int ebase = (t == 0) ? 0 : ssum[t - 1];
    loff[2 * t] = ebase;
    loff[2 * t + 1] = ebase + a0;
    __syncthreads();
    for (int i = t; i < 512; i += 256) lcur[i] = loff[i];
    int nbase = b << BSHIFT;
    for (int i = t; i < 512; i += 256) {
        int n = nbase + i;
        if (n < N_NODES) {
            cnt[n] = lcnt[i];
            offsets[n] = b * BCAP + loff[i];      // csr keeps per-bucket gaps
        }
    }
    __syncthreads();
    for (int i = t; i < m; i += 256) {
        unsigned p = src[i];
        int pos = atomicAdd(&lcur[p >> 17], 1);
        csr[(size_t)b * BCAP + pos] = (int)(p & 0x1FFFF);
    }
}

// ---------------------------------------------------------------------------
// GEMM1 (MFMA 16x16x32 bf16): [c1l | c1r] = x @ [W1_l | W1_r]
// c1l fp8-e4m3 [N,64] (gathered), c1r bf16 [N,64] (root).
__global__ __launch_bounds__(256) void gemm1_k(const float* __restrict__ x,
                                               const float* __restrict__ W1l,
                                               const float* __restrict__ W1r,
                                               unsigned char* __restrict__ c1l,
                                               __bf16* __restrict__ c1r) {
    __shared__ __bf16 Bt[128 * 136];   // B^T[n][k], stride 136 = 128+8 pad
    int tid = threadIdx.x;
    for (int idx = tid; idx < 8192; idx += 256) {   // W is [128][64] each
        int k = idx >> 6, n = idx & 63;
        Bt[n * 136 + k]        = (__bf16)W1l[idx];
        Bt[(n + 64) * 136 + k] = (__bf16)W1r[idx];
    }
    __syncthreads();

    int lane = tid & 63, wave = tid >> 6;
    int mbase = blockIdx.x * 64 + wave * 16;        // 1563 blocks * 64 rows
    int col  = lane & 15;
    int kgrp = (lane >> 4) << 3;                    // 0,8,16,24
    int mrow = mbase + col;
    int mclamp = mrow < N_NODES ? mrow : N_NODES - 1;
    const float* arow = x + (size_t)mclamp * 128;

    f32x4 acc[8];
#pragma unroll
    for (int i = 0; i < 8; ++i) acc[i] = (f32x4){0.f, 0.f, 0.f, 0.f};

#pragma unroll
    for (int ks = 0; ks < 4; ++ks) {
        int kk = ks * 32 + kgrp;
        f32x4 a0 = *(const f32x4*)(arow + kk);
        f32x4 a1 = *(const f32x4*)(arow + kk + 4);
        bf16x8 a;
#pragma unroll
        for (int i = 0; i < 4; ++i) { a[i] = (__bf16)a0[i]; a[i + 4] = (__bf16)a1[i]; }
#pragma unroll
        for (int nt = 0; nt < 8; ++nt) {
            bf16x8 b = *(const bf16x8*)(Bt + (nt * 16 + col) * 136 + kk);
            acc[nt] = __builtin_amdgcn_mfma_f32_16x16x32_bf16(a, b, acc[nt], 0, 0, 0);
        }
    }

    // C/D: col = lane&15, row = (lane>>4)*4 + reg   [m89-verified]
    int r0 = mbase + ((lane >> 4) << 2);
#pragma unroll
    for (int r = 0; r < 4; ++r) {
        int m = r0 + r;
        if (m < N_NODES) {
#pragma unroll
            for (int nt = 0; nt < 4; ++nt)
                c1l[(size_t)m * 64 + nt * 16 + col] = enc_fp8(acc[nt][r]);
#pragma unroll
            for (int nt = 4; nt < 8; ++nt)
                c1r[(size_t)m * 64 + (nt - 4) * 16 + col] = (__bf16)acc[nt][r];
        }
    }
}

// ---------------------------------------------------------------------------
// agg1 v4: 8 nodes/wave, 8 lanes/node, 8 feats/lane (8B fp8 loads).
// Lane-private feature sums -> NO cross-lane reduce; coalesced 16B h stores.
__global__ __launch_bounds__(256) void agg1_k(const unsigned char* __restrict__ c1l,
                                              const __bf16* __restrict__ c1r,
                                              const int* __restrict__ offsets,
                                              const int* __restrict__ cnt,
                                              const int* __restrict__ csr,
                                              const float* __restrict__ b1,
                                              __bf16* __restrict__ h) {
    int wave = blockIdx.x * 4 + (threadIdx.x >> 6); // 3125*4 = 12500 waves
    int lane = threadIdx.x & 63;
    int g = lane >> 3;                              // node group 0..7
    int n = wave * 8 + g;                           // exact 100000
    int f8b = (lane & 7) << 3;                      // feature base 0..56
    int beg = offsets[n], deg = cnt[n];
    int end = beg + deg;
    float sum[8];
#pragma unroll
    for (int j = 0; j < 8; ++j) sum[j] = 0.f;
    for (int e = beg; e < end; e += 4) {            // 4 outstanding loads/lane
#pragma unroll
        for (int u = 0; u < 4; ++u) {
            int i = e + u;
            if (i < end) {
                int s = csr[i];
                uint2 w = *(const uint2*)(c1l + (size_t)s * 64 + f8b);
                f32x2 p0 = __builtin_amdgcn_cvt_pk_f32_fp8(w.x, 0);
                f32x2 p1 = __builtin_amdgcn_cvt_pk_f32_fp8(w.x, 1);
                f32x2 p2 = __builtin_amdgcn_cvt_pk_f32_fp8(w.y, 0);
                f32x2 p3 = __builtin_amdgcn_cvt_pk_f32_fp8(w.y, 1);
                sum[0] += p0[0]; sum[1] += p0[1];
                sum[2] += p1[0]; sum[3] += p1[1];
                sum[4] += p2[0]; sum[5] += p2[1];
                sum[6] += p3[0]; sum[7] += p3[1];
            }
        }
    }
    float cf = deg > 0 ? (float)deg : 1.f;
    bf16x8 rv = *(const bf16x8*)(c1r + (size_t)n * 64 + f8b);
    bf16x8 o;
#pragma unroll
    for (int j = 0; j < 8; ++j) {
        float v = sum[j] / cf + (float)rv[j] + b1[f8b + j];
        o[j] = (__bf16)(v > 0.f ? v : 0.f);
    }
    *(bf16x8*)(h + (size_t)n * 64 + f8b) = o;       // coalesced 16B/lane
}

// ---------------------------------------------------------------------------
// GEMM2 (MFMA): [c2l | c2r] = h @ [W2_l | W2_r], h bf16 [N,64].
// c2l fp8-e4m3 [N,32], c2r fp32 [N,32] (kept exact: direct output path).
__global__ __launch_bounds__(256) void gemm2_k(const __bf16* __restrict__ h,
                                               const float* __restrict__ W2l,
                                               const float* __restrict__ W2r,
                                               unsigned char* __restrict__ c2l,
                                               float* __restrict__ c2r) {
    __shared__ __bf16 Bt[64 * 72];   // stride 72 = 64+8 pad
    int tid = threadIdx.x;
    for (int idx = tid; idx < 2048; idx += 256) {   // W2 is [64][32] each
        int k = idx >> 5, n = idx & 31;
        Bt[n * 72 + k]        = (__bf16)W2l[idx];
        Bt[(n + 32) * 72 + k] = (__bf16)W2r[idx];
    }
    __syncthreads();

    int lane = tid & 63, wave = tid >> 6;
    int mbase = blockIdx.x * 64 + wave * 16;
    int col  = lane & 15;
    int kgrp = (lane >> 4) << 3;
    int mrow = mbase + col;
    int mclamp = mrow < N_NODES ? mrow : N_NODES - 1;
    const __bf16* arow = h + (size_t)mclamp * 64;

    f32x4 acc[4];
#pragma unroll
    for (int i = 0; i < 4; ++i) acc[i] = (f32x4){0.f, 0.f, 0.f, 0.f};

#pragma unroll
    for (int ks = 0; ks < 2; ++ks) {
        int kk = ks * 32 + kgrp;
        bf16x8 a = *(const bf16x8*)(arow + kk);
#pragma unroll
        for (int nt = 0; nt < 4; ++nt) {
            bf16x8 b = *(const bf16x8*)(Bt + (nt * 16 + col) * 72 + kk);
            acc[nt] = __builtin_amdgcn_mfma_f32_16x16x32_bf16(a, b, acc[nt], 0, 0, 0);
        }
    }

    int r0 = mbase + ((lane >> 4) << 2);
#pragma unroll
    for (int r = 0; r < 4; ++r) {
        int m = r0 + r;
        if (m < N_NODES) {
#pragma unroll
            for (int nt = 0; nt < 2; ++nt)
                c2l[(size_t)m * 32 + nt * 16 + col] = enc_fp8(acc[nt][r]);
#pragma unroll
            for (int nt = 2; nt < 4; ++nt)
                c2r[(size_t)m * 32 + (nt - 2) * 16 + col] = acc[nt][r];
        }
    }
}

// ---------------------------------------------------------------------------
// agg2 v4 (fused final): 16 nodes/wave, 4 lanes/node, 8 feats/lane.
// Lane-private sums; risk head reduced with 2 shfls within the quad.
__global__ __launch_bounds__(256) void agg2_k(const unsigned char* __restrict__ c2l,
                                              const float* __restrict__ c2r,
                                              const int* __restrict__ offsets,
                                              const int* __restrict__ cnt,
                                              const int* __restrict__ csr,
                                              const float* __restrict__ b2,
                                              const float* __restrict__ Wh,
                                              const float* __restrict__ bh,
                                              float* __restrict__ out) {
    int wave = blockIdx.x * 4 + (threadIdx.x >> 6); // 1563*4 waves, 16 nodes each
    int lane = threadIdx.x & 63;
    int g = lane >> 2;                              // node group 0..15
    int n = wave * 16 + g;                          // covers 100032, guarded
    int f8b = (lane & 3) << 3;                      // feature base 0,8,16,24
    bool valid = n < N_NODES;
    int beg = 0, deg = 0;
    if (valid) { beg = offsets[n]; deg = cnt[n]; }
    int end = beg + deg;
    float sum[8];
#pragma unroll
    for (int j = 0; j < 8; ++j) sum[j] = 0.f;
    for (int e = beg; e < end; e += 4) {
#pragma unroll
        for (int u = 0; u < 4; ++u) {
            int i = e + u;
            if (i < end) {
                int s = csr[i];
                uint2 w = *(const uint2*)(c2l + (size_t)s * 32 + f8b);
                f32x2 p0 = __builtin_amdgcn_cvt_pk_f32_fp8(w.x, 0);
                f32x2 p1 = __builtin_amdgcn_cvt_pk_f32_fp8(w.x, 1);
                f32x2 p2 = __builtin_amdgcn_cvt_pk_f32_fp8(w.y, 0);
                f32x2 p3 = __builtin_amdgcn_cvt_pk_f32_fp8(w.y, 1);
                sum[0] += p0[0]; sum[1] += p0[1];
                sum[2] += p1[0]; sum[3] += p1[1];
                sum[4] += p2[0]; sum[5] += p2[1];
                sum[6] += p3[0]; sum[7] += p3[1];
            }
        }
    }
    float cf = deg > 0 ? (float)deg : 1.f;
    float r = 0.f;
    f32x4 o0, o1;
    if (valid) {
#pragma unroll
        for (int j = 0; j < 8; ++j) {
            float v = sum[j] / cf + c2r[(size_t)n * 32 + f8b + j] + b2[f8b + j];
            v = v > 0.f ? v : 0.f;
            if (j < 4) o0[j] = v; else o1[j - 4] = v;
            r += v * Wh[f8b + j];
        }
        *(f32x4*)(out + (size_t)n * 32 + f8b) = o0;
        *(f32x4*)(out + (size_t)n * 32 + f8b + 4) = o1;
    }
    r += __shfl_xor(r, 1, 64);                      // reduce within quad
    r += __shfl_xor(r, 2, 64);
    if (valid && (lane & 3) == 0)
        out[(size_t)N_NODES * 32 + n] = r + bh[0];
}

// ---------------------------------------------------------------------------
extern "C" void kernel_launch(void* const* d_in, const int* in_sizes, int n_in,
                              void* d_out, int out_size, void* d_ws, size_t ws_size,
                              hipStream_t stream) {
    const float* x   = (const float*)d_in[0];
    const int*   ei  = (const int*)d_in[1];
    const float* W1l = (const float*)d_in[2];
    const float* b1  = (const float*)d_in[3];
    const float* W1r = (const float*)d_in[4];
    const float* W2l = (const float*)d_in[5];
    const float* b2  = (const float*)d_in[6];
    const float* W2r = (const float*)d_in[7];
    const float* Wh  = (const float*)d_in[8];
    const float* bh  = (const float*)d_in[9];
    float* out = (float*)d_out;

    // workspace layout (bytes):
    //   c1l  @ 0          N*64*1 =  6,400,000  (fp8, gathered)
    //   c1r  @ 6.4M       N*64*2 = 12,800,000  (bf16 root)
    //   h    @ 19.2M      N*64*2 = 12,800,000  (bf16)
    //   c2l  @ 32.0M      N*32*1 =  3,200,000  (fp8, gathered)
    //   c2r  @ 35.2M      N*32*4 = 12,800,000  (fp32 root)
    //   cnt  @ 48.0M      N*4    =    400,000
    //   offs @ 48.4M      N*4    =    400,000
    //   gcur @ 48.8M      (pad 4096, zeroed)
    //   bbuf @ 48.804M    196*12288*4 = 9,633,792
    //   csr  @ 58.438M    196*12288*4 = 9,633,792
    char* ws = (char*)d_ws;
    unsigned char* c1l = (unsigned char*)(ws);
    __bf16*   c1r     = (__bf16*)(ws + 6400000);
    __bf16*   h       = (__bf16*)(ws + 19200000);
    unsigned char* c2l = (unsigned char*)(ws + 32000000);
    float*    c2r     = (float*)(ws + 35200000);
    int*      cnt     = (int*)(ws + 48000000);
    int*      offsets = (int*)(ws + 48400000);
    int*      gcur    = (int*)(ws + 48800000);
    unsigned* bbuf    = (unsigned*)(ws + 48804096);
    int*      csr     = (int*)(ws + 58437888);

    hipMemsetAsync(gcur, 0, NBUCK * 4, stream);

    partition_k<<<391, 256, 0, stream>>>(ei, gcur, bbuf);
    bucketcsr_k<<<NBUCK, 256, 0, stream>>>(bbuf, gcur, cnt, offsets, csr);
    gemm1_k    <<<1563, 256, 0, stream>>>(x, W1l, W1r, c1l, c1r);
    agg1_k     <<<3125, 256, 0, stream>>>(c1l, c1r, offsets, cnt, csr, b1, h);
    gemm2_k    <<<1563, 256, 0, stream>>>(h, W2l, W2r, c2l, c2r);
    agg2_k     <<<1563, 256, 0, stream>>>(c2l, c2r, offsets, cnt, csr, b2, Wh, bh, out);
}